// Round 1
// baseline (926.243 us; speedup 1.0000x reference)
//
#include <hip/hip_runtime.h>
#include <hip/hip_bf16.h>

#define BATCH 32768
#define NELEM 65536   // 2 * BATCH
#define FSTRIDE 584   // feat row stride (578 cols, padded)

typedef unsigned short u16;
typedef unsigned int u32;

__device__ __forceinline__ float bf2f(u16 u) {
    union { u32 u; float f; } c; c.u = ((u32)u) << 16; return c.f;
}
__device__ __forceinline__ u16 f2bf(float f) {
    union { float f; u32 u; } c; c.f = f;
    u32 x = c.u;
    u32 r = (x + 0x7fffu + ((x >> 16) & 1u)) >> 16;  // RNE
    return (u16)r;
}

// ---------------- K1: conv1 (pad1,k2) + relu + maxpool2 ----------------
// thread = (elem, pooled pos). out: pooled1[elem][pos(16)][ch(16)] fp32
__global__ __launch_bounds__(256) void k1_conv1(const int* __restrict__ frame,
        const float* __restrict__ w1, const float* __restrict__ b1,
        float* __restrict__ pooled1) {
    int t = blockIdx.x * 256 + threadIdx.x;
    int elem = t >> 4;
    int pos = t & 15;
    int py = pos >> 2, px = pos & 3;
    const int* fb = frame + elem * 147;
    float patch[3][3][3];  // [c][dy][dx]
    int iy0 = 2 * py - 1, ix0 = 2 * px - 1;
    #pragma unroll
    for (int dy = 0; dy < 3; ++dy) {
        int iy = iy0 + dy;
        #pragma unroll
        for (int dx = 0; dx < 3; ++dx) {
            int ix = ix0 + dx;
            bool ok = (iy >= 0 && iy < 7 && ix >= 0 && ix < 7);
            int base = (iy * 7 + ix) * 3;
            #pragma unroll
            for (int c = 0; c < 3; ++c)
                patch[c][dy][dx] = ok ? (float)fb[base + c] : 0.0f;
        }
    }
    float* outp = pooled1 + elem * 256 + pos * 16;
    for (int oc = 0; oc < 16; ++oc) {
        float bias = b1[oc];
        float m = 0.0f;  // post-relu values are >= 0
        #pragma unroll
        for (int sy = 0; sy < 2; ++sy)
        #pragma unroll
        for (int sx = 0; sx < 2; ++sx) {
            float acc = bias;
            #pragma unroll
            for (int ic = 0; ic < 3; ++ic)
            #pragma unroll
            for (int ky = 0; ky < 2; ++ky)
            #pragma unroll
            for (int kx = 0; kx < 2; ++kx)
                acc += patch[ic][sy + ky][sx + kx] * w1[oc * 12 + ic * 4 + ky * 2 + kx];
            acc = fmaxf(acc, 0.0f);
            m = fmaxf(m, acc);
        }
        outp[oc] = m;
    }
}

// ---------------- K2: conv2 (pad1,k2) + relu, positions 0..3 x 0..3 ----
// thread = (elem, oy*4+ox). out: c2act[elem][pos(16)][ch(32)] bf16
__global__ __launch_bounds__(256) void k2_conv2(const float* __restrict__ pooled1,
        const float* __restrict__ w2, const float* __restrict__ b2,
        u16* __restrict__ c2act) {
    int t = blockIdx.x * 256 + threadIdx.x;
    int elem = t >> 4;
    int pos = t & 15;
    int oy = pos >> 2, ox = pos & 3;
    const float* pb = pooled1 + elem * 256;
    float p[2][2][16];
    #pragma unroll
    for (int ky = 0; ky < 2; ++ky) {
        int iy = oy - 1 + ky;
        #pragma unroll
        for (int kx = 0; kx < 2; ++kx) {
            int ix = ox - 1 + kx;
            bool ok = (iy >= 0 && ix >= 0);  // iy,ix <= 3 always
            #pragma unroll
            for (int g = 0; g < 4; ++g) {
                float4 v;
                if (ok) v = *(const float4*)(pb + (iy * 4 + ix) * 16 + g * 4);
                else    v = make_float4(0.f, 0.f, 0.f, 0.f);
                p[ky][kx][g * 4 + 0] = v.x;
                p[ky][kx][g * 4 + 1] = v.y;
                p[ky][kx][g * 4 + 2] = v.z;
                p[ky][kx][g * 4 + 3] = v.w;
            }
        }
    }
    u16* outp = c2act + elem * 512 + pos * 32;
    for (int oc = 0; oc < 32; ++oc) {
        float acc = b2[oc];
        #pragma unroll
        for (int ic = 0; ic < 16; ++ic) {
            float4 w = *(const float4*)(w2 + oc * 64 + ic * 4);  // [ky][kx] = x,y,z,w
            acc += p[0][0][ic] * w.x + p[0][1][ic] * w.y
                 + p[1][0][ic] * w.z + p[1][1][ic] * w.w;
        }
        outp[oc] = f2bf(fmaxf(acc, 0.0f));
    }
}

// ---------------- K3: maxpool2 + conv3 + relu -> feat (bf16) -----------
// wave = 1 elem, lane = out channel c3. feat[elem][c3*9 + p], cols 576/577 = carried
__global__ __launch_bounds__(256) void k3_conv3(const u16* __restrict__ c2act,
        const float* __restrict__ w3, const float* __restrict__ b3,
        const int* __restrict__ ccol, const int* __restrict__ cobj,
        u16* __restrict__ feat) {
    int t = blockIdx.x * 256 + threadIdx.x;
    int elem = t >> 6;
    int c3 = t & 63;
    const u16* cb = c2act + elem * 512;
    float p2[32][4];  // [ic][iy*2+ix]
    #pragma unroll
    for (int py = 0; py < 2; ++py)
    #pragma unroll
    for (int px = 0; px < 2; ++px) {
        int q = py * 2 + px;
        #pragma unroll
        for (int g = 0; g < 8; ++g) {
            float m0 = 0.f, m1 = 0.f, m2 = 0.f, m3 = 0.f;  // inputs post-relu >= 0
            #pragma unroll
            for (int sy = 0; sy < 2; ++sy)
            #pragma unroll
            for (int sx = 0; sx < 2; ++sx) {
                ushort4 r = *(const ushort4*)(cb + ((2 * py + sy) * 4 + (2 * px + sx)) * 32 + g * 4);
                m0 = fmaxf(m0, bf2f(r.x));
                m1 = fmaxf(m1, bf2f(r.y));
                m2 = fmaxf(m2, bf2f(r.z));
                m3 = fmaxf(m3, bf2f(r.w));
            }
            p2[g * 4 + 0][q] = m0;
            p2[g * 4 + 1][q] = m1;
            p2[g * 4 + 2][q] = m2;
            p2[g * 4 + 3][q] = m3;
        }
    }
    float bias = b3[c3];
    float acc9[9];
    #pragma unroll
    for (int i = 0; i < 9; ++i) acc9[i] = bias;
    const float* wb = w3 + c3 * 128;
    #pragma unroll
    for (int ic = 0; ic < 32; ++ic) {
        float4 w = *(const float4*)(wb + ic * 4);
        float wv[4] = {w.x, w.y, w.z, w.w};
        #pragma unroll
        for (int oy = 0; oy < 3; ++oy)
        #pragma unroll
        for (int ox = 0; ox < 3; ++ox) {
            float s = 0.f;
            #pragma unroll
            for (int ky = 0; ky < 2; ++ky) {
                int iy = oy - 1 + ky;
                if (iy < 0 || iy > 1) continue;
                #pragma unroll
                for (int kx = 0; kx < 2; ++kx) {
                    int ix = ox - 1 + kx;
                    if (ix < 0 || ix > 1) continue;
                    s += p2[ic][iy * 2 + ix] * wv[ky * 2 + kx];
                }
            }
            acc9[oy * 3 + ox] += s;
        }
    }
    u16* outp = feat + (size_t)elem * FSTRIDE;
    #pragma unroll
    for (int i = 0; i < 9; ++i)
        outp[c3 * 9 + i] = f2bf(fmaxf(acc9[i], 0.0f));
    if (c3 == 0) outp[576] = f2bf((float)ccol[elem]);
    if (c3 == 1) outp[577] = f2bf((float)cobj[elem]);
}

// ---------------- K4: proj GEMM [65536 x 578] @ [578 -> 64] + relu ------
__global__ __launch_bounds__(128) void k4_proj(const u16* __restrict__ feat,
        const float* __restrict__ pw, const float* __restrict__ pb,
        float* __restrict__ emb) {
    __shared__ u16 As[128 * 34];
    __shared__ float Bs[32 * 65];
    int t = threadIdx.x;
    int m0 = blockIdx.x * 128;
    int tm = t >> 3;  // 0..15, rows tm*8 + i
    int tn = t & 7;   // 0..7, cols tn + 8*jj
    float acc[8][8];
    #pragma unroll
    for (int i = 0; i < 8; ++i)
        #pragma unroll
        for (int j = 0; j < 8; ++j) acc[i][j] = 0.f;

    for (int k0 = 0; k0 < 578; k0 += 32) {
        __syncthreads();
        for (int i = 0; i < 32; ++i) {
            int idx = i * 128 + t;
            int r = idx >> 5, kk = idx & 31;
            int k = k0 + kk;
            As[r * 34 + kk] = (k < 578) ? feat[(size_t)(m0 + r) * FSTRIDE + k] : (u16)0;
        }
        for (int i = 0; i < 16; ++i) {
            int idx = i * 128 + t;
            int kk = idx & 31, j = idx >> 5;
            int k = k0 + kk;
            Bs[kk * 65 + j] = (k < 578) ? pw[j * 578 + k] : 0.f;
        }
        __syncthreads();
        for (int kk = 0; kk < 32; ++kk) {
            float a[8], b[8];
            #pragma unroll
            for (int i = 0; i < 8; ++i) a[i] = bf2f(As[(tm * 8 + i) * 34 + kk]);
            #pragma unroll
            for (int j = 0; j < 8; ++j) b[j] = Bs[kk * 65 + tn + 8 * j];
            #pragma unroll
            for (int i = 0; i < 8; ++i)
                #pragma unroll
                for (int j = 0; j < 8; ++j)
                    acc[i][j] += a[i] * b[j];
        }
    }
    #pragma unroll
    for (int i = 0; i < 8; ++i) {
        int m = m0 + tm * 8 + i;
        #pragma unroll
        for (int j = 0; j < 8; ++j) {
            int jj = tn + 8 * j;
            emb[m * 64 + jj] = fmaxf(acc[i][j] + pb[jj], 0.f);
        }
    }
}

// ---------------- K5: dir_pos deltas -> extras[b][4] --------------------
__global__ __launch_bounds__(256) void k5_extras(const int* __restrict__ frame,
        float* __restrict__ extras) {
    int b = blockIdx.x * 256 + threadIdx.x;
    int d[2]; float posy[2], posx[2];
    for (int f = 0; f < 2; ++f) {
        const int* fb = frame + (size_t)(f * BATCH + b) * 147;
        int idx = 49;
        for (int cell = 0; cell < 49; ++cell) {
            int v = fb[cell * 3];
            if (idx == 49 && v == 10) idx = cell;
        }
        if (idx < 49) {
            d[f] = fb[idx * 3 + 2] & 3;
            posy[f] = (float)(idx / 7) / 6.0f;
            posx[f] = (float)(idx % 7) / 6.0f;
        } else {
            d[f] = 0; posy[f] = 0.5f; posx[f] = 0.5f;
        }
    }
    int delta = (d[1] - d[0] + 4) & 3;
    const float ANG = (float)(2.0 * 3.14159 / 4.0);
    float angle = (float)delta * ANG;
    extras[b * 4 + 0] = sinf(angle);
    extras[b * 4 + 1] = cosf(angle);
    extras[b * 4 + 2] = posy[1] - posy[0];
    extras[b * 4 + 3] = posx[1] - posx[0];
}

// ---------------- K6: h1 GEMM (gathered A, K=132) + bias + LN + relu ----
__global__ __launch_bounds__(128) void k6_h1(
        const float* __restrict__ emb, const float* __restrict__ extras,
        const float* __restrict__ w, const float* __restrict__ bias,
        const float* __restrict__ lng, const float* __restrict__ lnb,
        float* __restrict__ out) {
    __shared__ float As[64 * 133];
    __shared__ float Bs[32 * 129];
    __shared__ float mu_s[64], rs_s[64];
    int t = threadIdx.x;
    int b0 = blockIdx.x * 64;
    {
        int r = t >> 1, half = t & 1;
        int gb = b0 + r;
        for (int kk = 0; kk < 66; ++kk) {
            int k = half * 66 + kk;
            float v;
            if (k < 64)       v = emb[gb * 64 + k];
            else if (k < 128) v = emb[(BATCH + gb) * 64 + (k - 64)];
            else              v = extras[gb * 4 + (k - 128)];
            As[r * 133 + k] = v;
        }
    }
    int tm = t >> 4, tn = t & 15;  // rows tm*8+i, cols tn + 16*jj
    float acc[8][8];
    #pragma unroll
    for (int i = 0; i < 8; ++i)
        #pragma unroll
        for (int j = 0; j < 8; ++j) acc[i][j] = 0.f;

    for (int k0 = 0; k0 < 132; k0 += 32) {
        int kl = 132 - k0; if (kl > 32) kl = 32;
        __syncthreads();
        for (int i = 0; i < 32; ++i) {
            int idx = i * 128 + t;
            int j = idx >> 5, kk = idx & 31;
            Bs[kk * 129 + j] = (kk < kl) ? w[j * 132 + k0 + kk] : 0.f;
        }
        __syncthreads();
        for (int kk = 0; kk < kl; ++kk) {
            float a[8], b[8];
            #pragma unroll
            for (int i = 0; i < 8; ++i) a[i] = As[(tm * 8 + i) * 133 + k0 + kk];
            #pragma unroll
            for (int j = 0; j < 8; ++j) b[j] = Bs[kk * 129 + tn + 16 * j];
            #pragma unroll
            for (int i = 0; i < 8; ++i)
                #pragma unroll
                for (int j = 0; j < 8; ++j)
                    acc[i][j] += a[i] * b[j];
        }
    }
    __syncthreads();
    float* h = As;  // overlay: A-tile is dead
    #pragma unroll
    for (int i = 0; i < 8; ++i)
        #pragma unroll
        for (int j = 0; j < 8; ++j) {
            int jj = tn + 16 * j;
            h[(tm * 8 + i) * 129 + jj] = acc[i][j] + bias[jj];
        }
    __syncthreads();
    if (t < 64) {
        float s = 0.f;
        for (int k = 0; k < 128; ++k) s += h[t * 129 + k];
        float mu = s * (1.0f / 128.0f);
        float vs = 0.f;
        for (int k = 0; k < 128; ++k) { float d = h[t * 129 + k] - mu; vs += d * d; }
        mu_s[t] = mu;
        rs_s[t] = rsqrtf(vs * (1.0f / 128.0f) + 1e-5f);
    }
    __syncthreads();
    for (int i = 0; i < 64; ++i) {
        int o = i * 128 + t;
        int r = o >> 7, j = o & 127;
        float v = (h[r * 129 + j] - mu_s[r]) * rs_s[r] * lng[j] + lnb[j];
        out[(b0 + r) * 128 + j] = fmaxf(v, 0.f);
    }
}

// ---------------- K7: h2 GEMM [32768x128]@[128->128] + relu -------------
__global__ __launch_bounds__(128) void k7_h2(
        const float* __restrict__ in, const float* __restrict__ w,
        const float* __restrict__ bias, float* __restrict__ out) {
    __shared__ float As[64 * 129];
    __shared__ float Bs[32 * 129];
    int t = threadIdx.x;
    int b0 = blockIdx.x * 64;
    {
        int r = t >> 1, half = t & 1;
        for (int kk = 0; kk < 64; ++kk) {
            int k = half * 64 + kk;
            As[r * 129 + k] = in[(b0 + r) * 128 + k];
        }
    }
    int tm = t >> 4, tn = t & 15;
    float acc[8][8];
    #pragma unroll
    for (int i = 0; i < 8; ++i)
        #pragma unroll
        for (int j = 0; j < 8; ++j) acc[i][j] = 0.f;

    for (int k0 = 0; k0 < 128; k0 += 32) {
        __syncthreads();
        for (int i = 0; i < 32; ++i) {
            int idx = i * 128 + t;
            int j = idx >> 5, kk = idx & 31;
            Bs[kk * 129 + j] = w[j * 128 + k0 + kk];
        }
        __syncthreads();
        for (int kk = 0; kk < 32; ++kk) {
            float a[8], b[8];
            #pragma unroll
            for (int i = 0; i < 8; ++i) a[i] = As[(tm * 8 + i) * 129 + k0 + kk];
            #pragma unroll
            for (int j = 0; j < 8; ++j) b[j] = Bs[kk * 129 + tn + 16 * j];
            #pragma unroll
            for (int i = 0; i < 8; ++i)
                #pragma unroll
                for (int j = 0; j < 8; ++j)
                    acc[i][j] += a[i] * b[j];
        }
    }
    #pragma unroll
    for (int i = 0; i < 8; ++i)
        #pragma unroll
        for (int j = 0; j < 8; ++j) {
            int jj = tn + 16 * j;
            out[(b0 + tm * 8 + i) * 128 + jj] = fmaxf(acc[i][j] + bias[jj], 0.f);
        }
}

// ---------------- K8: h3 [32768x128]@[128->7] ---------------------------
__global__ __launch_bounds__(256) void k8_h3(const float* __restrict__ in,
        const float* __restrict__ w, const float* __restrict__ bias,
        float* __restrict__ out) {
    __shared__ float As[64 * 129];
    int t = threadIdx.x;
    int b0 = blockIdx.x * 64;
    for (int i = 0; i < 32; ++i) {
        int idx = i * 256 + t;
        int r = idx >> 7, k = idx & 127;
        As[r * 129 + k] = in[(b0 + r) * 128 + k];
    }
    __syncthreads();
    int r = t & 63, jg = t >> 6;  // jg 0..3 (wave-uniform)
    #pragma unroll
    for (int u = 0; u < 2; ++u) {
        int j = jg * 2 + u;
        if (j < 7) {
            float acc = bias[j];
            for (int k = 0; k < 128; ++k)
                acc += As[r * 129 + k] * w[j * 128 + k];
            out[(b0 + r) * 7 + j] = acc;
        }
    }
}

extern "C" void kernel_launch(void* const* d_in, const int* in_sizes, int n_in,
                              void* d_out, int out_size, void* d_ws, size_t ws_size,
                              hipStream_t stream) {
    const int*   frame = (const int*)d_in[0];
    const int*   ccol  = (const int*)d_in[1];
    const int*   cobj  = (const int*)d_in[2];
    const float* w1    = (const float*)d_in[3];
    const float* b1    = (const float*)d_in[4];
    const float* w2    = (const float*)d_in[5];
    const float* b2    = (const float*)d_in[6];
    const float* w3    = (const float*)d_in[7];
    const float* b3    = (const float*)d_in[8];
    const float* pw    = (const float*)d_in[9];
    const float* pb    = (const float*)d_in[10];
    const float* h1w   = (const float*)d_in[11];
    const float* h1b   = (const float*)d_in[12];
    const float* lng   = (const float*)d_in[13];
    const float* lnb   = (const float*)d_in[14];
    const float* h2w   = (const float*)d_in[15];
    const float* h2b   = (const float*)d_in[16];
    const float* h3w   = (const float*)d_in[17];
    const float* h3b   = (const float*)d_in[18];
    float* out = (float*)d_out;

    char* ws = (char*)d_ws;
    // [0, 64MB): c2act (bf16)  -- later reused for emb/extras/ws7/ws8
    // [64MB, 128MB): pooled1 (fp32) -- later overlaid by feat (bf16, 76.5MB)
    u16*   c2act   = (u16*)(ws + 0);
    float* pooled1 = (float*)(ws + (1ull << 26));
    u16*   feat    = (u16*)(ws + (1ull << 26));              // overlays pooled1 (dead)
    float* emb     = (float*)(ws + 0);                       // overlays c2act (dead)
    float* extras  = (float*)(ws + 16777216);
    float* h1out   = (float*)(ws + 17301504);
    float* h2out   = (float*)(ws + 34078720);
    // peak ws usage = 64MB + 76.5MB = ~137 MB

    k1_conv1<<<4096, 256, 0, stream>>>(frame, w1, b1, pooled1);
    k2_conv2<<<4096, 256, 0, stream>>>(pooled1, w2, b2, c2act);
    k3_conv3<<<16384, 256, 0, stream>>>(c2act, w3, b3, ccol, cobj, feat);
    k4_proj<<<512, 128, 0, stream>>>(feat, pw, pb, emb);
    k5_extras<<<128, 256, 0, stream>>>(frame, extras);
    k6_h1<<<512, 128, 0, stream>>>(emb, extras, h1w, h1b, lng, lnb, h1out);
    k7_h2<<<512, 128, 0, stream>>>(h1out, h2w, h2b, h2out);
    k8_h3<<<512, 256, 0, stream>>>(h2out, h3w, h3b, out);
}

// Round 2
// 669.898 us; speedup vs baseline: 1.3827x; 1.3827x over previous
//
#include <hip/hip_runtime.h>
#include <hip/hip_bf16.h>

#define BATCH 32768
#define NELEM 65536   // 2 * BATCH
#define FSTRIDE 584   // feat row stride (578 cols, padded)

typedef unsigned short u16;
typedef unsigned int u32;

__device__ __forceinline__ float bf2f(u16 u) {
    union { u32 u; float f; } c; c.u = ((u32)u) << 16; return c.f;
}
__device__ __forceinline__ u16 f2bf(float f) {
    union { float f; u32 u; } c; c.f = f;
    u32 x = c.u;
    u32 r = (x + 0x7fffu + ((x >> 16) & 1u)) >> 16;  // RNE
    return (u16)r;
}

// ---------------- K1: conv1 (pad1,k2) + relu + maxpool2 ----------------
// thread = (elem, pooled pos). out: pooled1[elem][pos(16)][ch(16)] fp32
__global__ __launch_bounds__(256) void k1_conv1(const int* __restrict__ frame,
        const float* __restrict__ w1, const float* __restrict__ b1,
        float* __restrict__ pooled1) {
    int t = blockIdx.x * 256 + threadIdx.x;
    int elem = t >> 4;
    int pos = t & 15;
    int py = pos >> 2, px = pos & 3;
    const int* fb = frame + elem * 147;
    float patch[3][3][3];  // [c][dy][dx]
    int iy0 = 2 * py - 1, ix0 = 2 * px - 1;
    #pragma unroll
    for (int dy = 0; dy < 3; ++dy) {
        int iy = iy0 + dy;
        #pragma unroll
        for (int dx = 0; dx < 3; ++dx) {
            int ix = ix0 + dx;
            bool ok = (iy >= 0 && iy < 7 && ix >= 0 && ix < 7);
            int base = (iy * 7 + ix) * 3;
            #pragma unroll
            for (int c = 0; c < 3; ++c)
                patch[c][dy][dx] = ok ? (float)fb[base + c] : 0.0f;
        }
    }
    float* outp = pooled1 + elem * 256 + pos * 16;
    for (int oc = 0; oc < 16; ++oc) {
        float bias = b1[oc];
        float m = 0.0f;  // post-relu values are >= 0
        #pragma unroll
        for (int sy = 0; sy < 2; ++sy)
        #pragma unroll
        for (int sx = 0; sx < 2; ++sx) {
            float acc = bias;
            #pragma unroll
            for (int ic = 0; ic < 3; ++ic)
            #pragma unroll
            for (int ky = 0; ky < 2; ++ky)
            #pragma unroll
            for (int kx = 0; kx < 2; ++kx)
                acc += patch[ic][sy + ky][sx + kx] * w1[oc * 12 + ic * 4 + ky * 2 + kx];
            acc = fmaxf(acc, 0.0f);
            m = fmaxf(m, acc);
        }
        outp[oc] = m;
    }
}

// ---------------- K2: conv2 (pad1,k2) + relu, positions 0..3 x 0..3 ----
// thread = (elem, oy*4+ox). out: c2act[elem][pos(16)][ch(32)] bf16
__global__ __launch_bounds__(256) void k2_conv2(const float* __restrict__ pooled1,
        const float* __restrict__ w2, const float* __restrict__ b2,
        u16* __restrict__ c2act) {
    int t = blockIdx.x * 256 + threadIdx.x;
    int elem = t >> 4;
    int pos = t & 15;
    int oy = pos >> 2, ox = pos & 3;
    const float* pb = pooled1 + elem * 256;
    float p[2][2][16];
    #pragma unroll
    for (int ky = 0; ky < 2; ++ky) {
        int iy = oy - 1 + ky;
        #pragma unroll
        for (int kx = 0; kx < 2; ++kx) {
            int ix = ox - 1 + kx;
            bool ok = (iy >= 0 && ix >= 0);  // iy,ix <= 3 always
            #pragma unroll
            for (int g = 0; g < 4; ++g) {
                float4 v;
                if (ok) v = *(const float4*)(pb + (iy * 4 + ix) * 16 + g * 4);
                else    v = make_float4(0.f, 0.f, 0.f, 0.f);
                p[ky][kx][g * 4 + 0] = v.x;
                p[ky][kx][g * 4 + 1] = v.y;
                p[ky][kx][g * 4 + 2] = v.z;
                p[ky][kx][g * 4 + 3] = v.w;
            }
        }
    }
    u16* outp = c2act + elem * 512 + pos * 32;
    for (int oc = 0; oc < 32; ++oc) {
        float acc = b2[oc];
        #pragma unroll
        for (int ic = 0; ic < 16; ++ic) {
            float4 w = *(const float4*)(w2 + oc * 64 + ic * 4);  // [ky][kx] = x,y,z,w
            acc += p[0][0][ic] * w.x + p[0][1][ic] * w.y
                 + p[1][0][ic] * w.z + p[1][1][ic] * w.w;
        }
        outp[oc] = f2bf(fmaxf(acc, 0.0f));
    }
}

// ---------------- K3: maxpool2 + conv3 + relu -> feat (bf16) -----------
// Block = 256 thr, 8 chunks x 4 elems. Cooperative pooling into LDS (each
// c2act value read ONCE), w3 staged transposed [k][oc] stride 65 (bank-
// conflict-free both phases). Compute: wave = elem, lane = oc.
#define K3_EPC 4
#define K3_CHUNKS 8
__global__ __launch_bounds__(256) void k3_conv3(const u16* __restrict__ c2act,
        const float* __restrict__ w3, const float* __restrict__ b3,
        const int* __restrict__ ccol, const int* __restrict__ cobj,
        u16* __restrict__ feat) {
    __shared__ float wTs[128 * 65];          // [k = ic*4+tap][oc], stride 65
    __shared__ float pooled[K3_EPC * 128];   // [e][ic][q], q = iy*2+ix
    int t = threadIdx.x;
    // stage w3 transposed: global idx coalesced, LDS write stride 65 (bank-free)
    for (int i = 0; i < 32; ++i) {
        int idx = i * 256 + t;               // oc = idx>>7, k = idx&127
        wTs[(idx & 127) * 65 + (idx >> 7)] = w3[idx];
    }
    int oc = t & 63;
    int le = t >> 6;                         // local elem 0..3
    float bias = b3[oc];
    int eb = blockIdx.x * (K3_EPC * K3_CHUNKS);
    for (int c = 0; c < K3_CHUNKS; ++c) {
        int e0 = eb + c * K3_EPC;
        __syncthreads();                     // pooled reusable (also covers wTs 1st iter)
        #pragma unroll
        for (int j = 0; j < 2; ++j) {
            int flat = t * 2 + j;            // [e(2b)][ic(5b)][q(2b)]
            int pe = flat >> 7;
            int ic = (flat >> 2) & 31;
            int q  = flat & 3;
            int py = q >> 1, px = q & 1;
            const u16* cb = c2act + (size_t)(e0 + pe) * 512 + ic;
            float m = 0.f;                   // post-relu inputs >= 0
            #pragma unroll
            for (int sy = 0; sy < 2; ++sy)
                #pragma unroll
                for (int sx = 0; sx < 2; ++sx)
                    m = fmaxf(m, bf2f(cb[((2 * py + sy) * 4 + 2 * px + sx) * 32]));
            pooled[flat] = m;
        }
        __syncthreads();
        float acc9[9];
        #pragma unroll
        for (int i = 0; i < 9; ++i) acc9[i] = bias;
        const float* pp = pooled + le * 128;
        #pragma unroll
        for (int ic = 0; ic < 32; ++ic) {
            float4 p = *(const float4*)(pp + ic * 4);   // broadcast read
            float pv[4] = {p.x, p.y, p.z, p.w};
            float w[4];
            #pragma unroll
            for (int tap = 0; tap < 4; ++tap)
                w[tap] = wTs[(ic * 4 + tap) * 65 + oc]; // conflict-free
            #pragma unroll
            for (int q = 0; q < 4; ++q) {
                int iy = q >> 1, ix = q & 1;
                #pragma unroll
                for (int ky = 0; ky < 2; ++ky)
                    #pragma unroll
                    for (int kx = 0; kx < 2; ++kx)
                        acc9[(iy + 1 - ky) * 3 + (ix + 1 - kx)] += pv[q] * w[ky * 2 + kx];
            }
        }
        u16* outp = feat + (size_t)(e0 + le) * FSTRIDE;
        #pragma unroll
        for (int i = 0; i < 9; ++i)
            outp[oc * 9 + i] = f2bf(fmaxf(acc9[i], 0.0f));
        if (oc == 0) outp[576] = f2bf((float)ccol[e0 + le]);
        if (oc == 1) outp[577] = f2bf((float)cobj[e0 + le]);
    }
}

// ---------------- K4: proj GEMM [65536 x 578] @ [578 -> 64] + relu ------
__global__ __launch_bounds__(128) void k4_proj(const u16* __restrict__ feat,
        const float* __restrict__ pw, const float* __restrict__ pb,
        float* __restrict__ emb) {
    __shared__ u16 As[128 * 34];
    __shared__ float Bs[32 * 65];
    int t = threadIdx.x;
    int m0 = blockIdx.x * 128;
    int tm = t >> 3;  // 0..15, rows tm*8 + i
    int tn = t & 7;   // 0..7, cols tn + 8*jj
    float acc[8][8];
    #pragma unroll
    for (int i = 0; i < 8; ++i)
        #pragma unroll
        for (int j = 0; j < 8; ++j) acc[i][j] = 0.f;

    for (int k0 = 0; k0 < 578; k0 += 32) {
        __syncthreads();
        for (int i = 0; i < 32; ++i) {
            int idx = i * 128 + t;
            int r = idx >> 5, kk = idx & 31;
            int k = k0 + kk;
            As[r * 34 + kk] = (k < 578) ? feat[(size_t)(m0 + r) * FSTRIDE + k] : (u16)0;
        }
        for (int i = 0; i < 16; ++i) {
            int idx = i * 128 + t;
            int kk = idx & 31, j = idx >> 5;
            int k = k0 + kk;
            Bs[kk * 65 + j] = (k < 578) ? pw[j * 578 + k] : 0.f;
        }
        __syncthreads();
        for (int kk = 0; kk < 32; ++kk) {
            float a[8], b[8];
            #pragma unroll
            for (int i = 0; i < 8; ++i) a[i] = bf2f(As[(tm * 8 + i) * 34 + kk]);
            #pragma unroll
            for (int j = 0; j < 8; ++j) b[j] = Bs[kk * 65 + tn + 8 * j];
            #pragma unroll
            for (int i = 0; i < 8; ++i)
                #pragma unroll
                for (int j = 0; j < 8; ++j)
                    acc[i][j] += a[i] * b[j];
        }
    }
    #pragma unroll
    for (int i = 0; i < 8; ++i) {
        int m = m0 + tm * 8 + i;
        #pragma unroll
        for (int j = 0; j < 8; ++j) {
            int jj = tn + 8 * j;
            emb[m * 64 + jj] = fmaxf(acc[i][j] + pb[jj], 0.f);
        }
    }
}

// ---------------- K5: dir_pos deltas -> extras[b][4] --------------------
__global__ __launch_bounds__(256) void k5_extras(const int* __restrict__ frame,
        float* __restrict__ extras) {
    int b = blockIdx.x * 256 + threadIdx.x;
    int d[2]; float posy[2], posx[2];
    for (int f = 0; f < 2; ++f) {
        const int* fb = frame + (size_t)(f * BATCH + b) * 147;
        int idx = 49;
        for (int cell = 0; cell < 49; ++cell) {
            int v = fb[cell * 3];
            if (idx == 49 && v == 10) idx = cell;
        }
        if (idx < 49) {
            d[f] = fb[idx * 3 + 2] & 3;
            posy[f] = (float)(idx / 7) / 6.0f;
            posx[f] = (float)(idx % 7) / 6.0f;
        } else {
            d[f] = 0; posy[f] = 0.5f; posx[f] = 0.5f;
        }
    }
    int delta = (d[1] - d[0] + 4) & 3;
    const float ANG = (float)(2.0 * 3.14159 / 4.0);
    float angle = (float)delta * ANG;
    extras[b * 4 + 0] = sinf(angle);
    extras[b * 4 + 1] = cosf(angle);
    extras[b * 4 + 2] = posy[1] - posy[0];
    extras[b * 4 + 3] = posx[1] - posx[0];
}

// ---------------- K6: h1 GEMM (gathered A, K=132) + bias + LN + relu ----
__global__ __launch_bounds__(128) void k6_h1(
        const float* __restrict__ emb, const float* __restrict__ extras,
        const float* __restrict__ w, const float* __restrict__ bias,
        const float* __restrict__ lng, const float* __restrict__ lnb,
        float* __restrict__ out) {
    __shared__ float As[64 * 133];
    __shared__ float Bs[32 * 129];
    __shared__ float mu_s[64], rs_s[64];
    int t = threadIdx.x;
    int b0 = blockIdx.x * 64;
    {
        int r = t >> 1, half = t & 1;
        int gb = b0 + r;
        for (int kk = 0; kk < 66; ++kk) {
            int k = half * 66 + kk;
            float v;
            if (k < 64)       v = emb[gb * 64 + k];
            else if (k < 128) v = emb[(BATCH + gb) * 64 + (k - 64)];
            else              v = extras[gb * 4 + (k - 128)];
            As[r * 133 + k] = v;
        }
    }
    int tm = t >> 4, tn = t & 15;  // rows tm*8+i, cols tn + 16*jj
    float acc[8][8];
    #pragma unroll
    for (int i = 0; i < 8; ++i)
        #pragma unroll
        for (int j = 0; j < 8; ++j) acc[i][j] = 0.f;

    for (int k0 = 0; k0 < 132; k0 += 32) {
        int kl = 132 - k0; if (kl > 32) kl = 32;
        __syncthreads();
        for (int i = 0; i < 32; ++i) {
            int idx = i * 128 + t;
            int j = idx >> 5, kk = idx & 31;
            Bs[kk * 129 + j] = (kk < kl) ? w[j * 132 + k0 + kk] : 0.f;
        }
        __syncthreads();
        for (int kk = 0; kk < kl; ++kk) {
            float a[8], b[8];
            #pragma unroll
            for (int i = 0; i < 8; ++i) a[i] = As[(tm * 8 + i) * 133 + k0 + kk];
            #pragma unroll
            for (int j = 0; j < 8; ++j) b[j] = Bs[kk * 129 + tn + 16 * j];
            #pragma unroll
            for (int i = 0; i < 8; ++i)
                #pragma unroll
                for (int j = 0; j < 8; ++j)
                    acc[i][j] += a[i] * b[j];
        }
    }
    __syncthreads();
    float* h = As;  // overlay: A-tile is dead
    #pragma unroll
    for (int i = 0; i < 8; ++i)
        #pragma unroll
        for (int j = 0; j < 8; ++j) {
            int jj = tn + 16 * j;
            h[(tm * 8 + i) * 129 + jj] = acc[i][j] + bias[jj];
        }
    __syncthreads();
    if (t < 64) {
        float s = 0.f;
        for (int k = 0; k < 128; ++k) s += h[t * 129 + k];
        float mu = s * (1.0f / 128.0f);
        float vs = 0.f;
        for (int k = 0; k < 128; ++k) { float d = h[t * 129 + k] - mu; vs += d * d; }
        mu_s[t] = mu;
        rs_s[t] = rsqrtf(vs * (1.0f / 128.0f) + 1e-5f);
    }
    __syncthreads();
    for (int i = 0; i < 64; ++i) {
        int o = i * 128 + t;
        int r = o >> 7, j = o & 127;
        float v = (h[r * 129 + j] - mu_s[r]) * rs_s[r] * lng[j] + lnb[j];
        out[(b0 + r) * 128 + j] = fmaxf(v, 0.f);
    }
}

// ---------------- K7: h2 GEMM [32768x128]@[128->128] + relu -------------
__global__ __launch_bounds__(128) void k7_h2(
        const float* __restrict__ in, const float* __restrict__ w,
        const float* __restrict__ bias, float* __restrict__ out) {
    __shared__ float As[64 * 129];
    __shared__ float Bs[32 * 129];
    int t = threadIdx.x;
    int b0 = blockIdx.x * 64;
    {
        int r = t >> 1, half = t & 1;
        for (int kk = 0; kk < 64; ++kk) {
            int k = half * 64 + kk;
            As[r * 129 + k] = in[(b0 + r) * 128 + k];
        }
    }
    int tm = t >> 4, tn = t & 15;
    float acc[8][8];
    #pragma unroll
    for (int i = 0; i < 8; ++i)
        #pragma unroll
        for (int j = 0; j < 8; ++j) acc[i][j] = 0.f;

    for (int k0 = 0; k0 < 128; k0 += 32) {
        __syncthreads();
        for (int i = 0; i < 32; ++i) {
            int idx = i * 128 + t;
            int j = idx >> 5, kk = idx & 31;
            Bs[kk * 129 + j] = w[j * 128 + k0 + kk];
        }
        __syncthreads();
        for (int kk = 0; kk < 32; ++kk) {
            float a[8], b[8];
            #pragma unroll
            for (int i = 0; i < 8; ++i) a[i] = As[(tm * 8 + i) * 129 + k0 + kk];
            #pragma unroll
            for (int j = 0; j < 8; ++j) b[j] = Bs[kk * 129 + tn + 16 * j];
            #pragma unroll
            for (int i = 0; i < 8; ++i)
                #pragma unroll
                for (int j = 0; j < 8; ++j)
                    acc[i][j] += a[i] * b[j];
        }
    }
    #pragma unroll
    for (int i = 0; i < 8; ++i)
        #pragma unroll
        for (int j = 0; j < 8; ++j) {
            int jj = tn + 16 * j;
            out[(b0 + tm * 8 + i) * 128 + jj] = fmaxf(acc[i][j] + bias[jj], 0.f);
        }
}

// ---------------- K8: h3 [32768x128]@[128->7] ---------------------------
__global__ __launch_bounds__(256) void k8_h3(const float* __restrict__ in,
        const float* __restrict__ w, const float* __restrict__ bias,
        float* __restrict__ out) {
    __shared__ float As[64 * 129];
    int t = threadIdx.x;
    int b0 = blockIdx.x * 64;
    for (int i = 0; i < 32; ++i) {
        int idx = i * 256 + t;
        int r = idx >> 7, k = idx & 127;
        As[r * 129 + k] = in[(b0 + r) * 128 + k];
    }
    __syncthreads();
    int r = t & 63, jg = t >> 6;  // jg 0..3 (wave-uniform)
    #pragma unroll
    for (int u = 0; u < 2; ++u) {
        int j = jg * 2 + u;
        if (j < 7) {
            float acc = bias[j];
            for (int k = 0; k < 128; ++k)
                acc += As[r * 129 + k] * w[j * 128 + k];
            out[(b0 + r) * 7 + j] = acc;
        }
    }
}

extern "C" void kernel_launch(void* const* d_in, const int* in_sizes, int n_in,
                              void* d_out, int out_size, void* d_ws, size_t ws_size,
                              hipStream_t stream) {
    const int*   frame = (const int*)d_in[0];
    const int*   ccol  = (const int*)d_in[1];
    const int*   cobj  = (const int*)d_in[2];
    const float* w1    = (const float*)d_in[3];
    const float* b1    = (const float*)d_in[4];
    const float* w2    = (const float*)d_in[5];
    const float* b2    = (const float*)d_in[6];
    const float* w3    = (const float*)d_in[7];
    const float* b3    = (const float*)d_in[8];
    const float* pw    = (const float*)d_in[9];
    const float* pb    = (const float*)d_in[10];
    const float* h1w   = (const float*)d_in[11];
    const float* h1b   = (const float*)d_in[12];
    const float* lng   = (const float*)d_in[13];
    const float* lnb   = (const float*)d_in[14];
    const float* h2w   = (const float*)d_in[15];
    const float* h2b   = (const float*)d_in[16];
    const float* h3w   = (const float*)d_in[17];
    const float* h3b   = (const float*)d_in[18];
    float* out = (float*)d_out;

    char* ws = (char*)d_ws;
    u16*   c2act   = (u16*)(ws + 0);
    float* pooled1 = (float*)(ws + (1ull << 26));
    u16*   feat    = (u16*)(ws + (1ull << 26));              // overlays pooled1 (dead)
    float* emb     = (float*)(ws + 0);                       // overlays c2act (dead)
    float* extras  = (float*)(ws + 16777216);
    float* h1out   = (float*)(ws + 17301504);
    float* h2out   = (float*)(ws + 34078720);

    k1_conv1<<<4096, 256, 0, stream>>>(frame, w1, b1, pooled1);
    k2_conv2<<<4096, 256, 0, stream>>>(pooled1, w2, b2, c2act);
    k3_conv3<<<2048, 256, 0, stream>>>(c2act, w3, b3, ccol, cobj, feat);
    k4_proj<<<512, 128, 0, stream>>>(feat, pw, pb, emb);
    k5_extras<<<128, 256, 0, stream>>>(frame, extras);
    k6_h1<<<512, 128, 0, stream>>>(emb, extras, h1w, h1b, lng, lnb, h1out);
    k7_h2<<<512, 128, 0, stream>>>(h1out, h2w, h2b, h2out);
    k8_h3<<<512, 256, 0, stream>>>(h2out, h3w, h3b, out);
}

// Round 3
// 475.836 us; speedup vs baseline: 1.9466x; 1.4078x over previous
//
#include <hip/hip_runtime.h>
#include <hip/hip_bf16.h>

#define BATCH 32768
#define NELEM 65536   // 2 * BATCH
#define FSTRIDE 584   // feat row stride (578 cols + 6 zeroed pad cols)

typedef unsigned short u16;
typedef unsigned int u32;
typedef __attribute__((ext_vector_type(8))) short bf16x8;
typedef __attribute__((ext_vector_type(4))) float f32x4;

__device__ __forceinline__ float bf2f(u16 u) {
    union { u32 u; float f; } c; c.u = ((u32)u) << 16; return c.f;
}
__device__ __forceinline__ u16 f2bf(float f) {
    union { float f; u32 u; } c; c.f = f;
    u32 x = c.u;
    u32 r = (x + 0x7fffu + ((x >> 16) & 1u)) >> 16;  // RNE
    return (u16)r;
}

// ---------------- K1: conv1 (pad1,k2) + relu + maxpool2 ----------------
__global__ __launch_bounds__(256) void k1_conv1(const int* __restrict__ frame,
        const float* __restrict__ w1, const float* __restrict__ b1,
        float* __restrict__ pooled1) {
    int t = blockIdx.x * 256 + threadIdx.x;
    int elem = t >> 4;
    int pos = t & 15;
    int py = pos >> 2, px = pos & 3;
    const int* fb = frame + elem * 147;
    float patch[3][3][3];  // [c][dy][dx]
    int iy0 = 2 * py - 1, ix0 = 2 * px - 1;
    #pragma unroll
    for (int dy = 0; dy < 3; ++dy) {
        int iy = iy0 + dy;
        #pragma unroll
        for (int dx = 0; dx < 3; ++dx) {
            int ix = ix0 + dx;
            bool ok = (iy >= 0 && iy < 7 && ix >= 0 && ix < 7);
            int base = (iy * 7 + ix) * 3;
            #pragma unroll
            for (int c = 0; c < 3; ++c)
                patch[c][dy][dx] = ok ? (float)fb[base + c] : 0.0f;
        }
    }
    float* outp = pooled1 + elem * 256 + pos * 16;
    for (int oc = 0; oc < 16; ++oc) {
        float bias = b1[oc];
        float m = 0.0f;
        #pragma unroll
        for (int sy = 0; sy < 2; ++sy)
        #pragma unroll
        for (int sx = 0; sx < 2; ++sx) {
            float acc = bias;
            #pragma unroll
            for (int ic = 0; ic < 3; ++ic)
            #pragma unroll
            for (int ky = 0; ky < 2; ++ky)
            #pragma unroll
            for (int kx = 0; kx < 2; ++kx)
                acc += patch[ic][sy + ky][sx + kx] * w1[oc * 12 + ic * 4 + ky * 2 + kx];
            acc = fmaxf(acc, 0.0f);
            m = fmaxf(m, acc);
        }
        outp[oc] = m;
    }
}

// ---------------- K2: conv2 (pad1,k2) + relu ---------------------------
__global__ __launch_bounds__(256) void k2_conv2(const float* __restrict__ pooled1,
        const float* __restrict__ w2, const float* __restrict__ b2,
        u16* __restrict__ c2act) {
    int t = blockIdx.x * 256 + threadIdx.x;
    int elem = t >> 4;
    int pos = t & 15;
    int oy = pos >> 2, ox = pos & 3;
    const float* pb = pooled1 + elem * 256;
    float p[2][2][16];
    #pragma unroll
    for (int ky = 0; ky < 2; ++ky) {
        int iy = oy - 1 + ky;
        #pragma unroll
        for (int kx = 0; kx < 2; ++kx) {
            int ix = ox - 1 + kx;
            bool ok = (iy >= 0 && ix >= 0);
            #pragma unroll
            for (int g = 0; g < 4; ++g) {
                float4 v;
                if (ok) v = *(const float4*)(pb + (iy * 4 + ix) * 16 + g * 4);
                else    v = make_float4(0.f, 0.f, 0.f, 0.f);
                p[ky][kx][g * 4 + 0] = v.x;
                p[ky][kx][g * 4 + 1] = v.y;
                p[ky][kx][g * 4 + 2] = v.z;
                p[ky][kx][g * 4 + 3] = v.w;
            }
        }
    }
    u16* outp = c2act + elem * 512 + pos * 32;
    for (int oc = 0; oc < 32; ++oc) {
        float acc = b2[oc];
        #pragma unroll
        for (int ic = 0; ic < 16; ++ic) {
            float4 w = *(const float4*)(w2 + oc * 64 + ic * 4);
            acc += p[0][0][ic] * w.x + p[0][1][ic] * w.y
                 + p[1][0][ic] * w.z + p[1][1][ic] * w.w;
        }
        outp[oc] = f2bf(fmaxf(acc, 0.0f));
    }
}

// ---------------- K3: maxpool2 + conv3 + relu -> feat (bf16) -----------
#define K3_EPC 4
#define K3_CHUNKS 8
__global__ __launch_bounds__(256) void k3_conv3(const u16* __restrict__ c2act,
        const float* __restrict__ w3, const float* __restrict__ b3,
        const int* __restrict__ ccol, const int* __restrict__ cobj,
        u16* __restrict__ feat) {
    __shared__ float wTs[128 * 65];          // [k][oc], stride 65
    __shared__ float pooled[K3_EPC * 128];   // [e][ic][q]
    int t = threadIdx.x;
    for (int i = 0; i < 32; ++i) {
        int idx = i * 256 + t;
        wTs[(idx & 127) * 65 + (idx >> 7)] = w3[idx];
    }
    int oc = t & 63;
    int le = t >> 6;
    float bias = b3[oc];
    int eb = blockIdx.x * (K3_EPC * K3_CHUNKS);
    for (int c = 0; c < K3_CHUNKS; ++c) {
        int e0 = eb + c * K3_EPC;
        __syncthreads();
        #pragma unroll
        for (int j = 0; j < 2; ++j) {
            int flat = t * 2 + j;
            int pe = flat >> 7;
            int ic = (flat >> 2) & 31;
            int q  = flat & 3;
            int py = q >> 1, px = q & 1;
            const u16* cb = c2act + (size_t)(e0 + pe) * 512 + ic;
            float m = 0.f;
            #pragma unroll
            for (int sy = 0; sy < 2; ++sy)
                #pragma unroll
                for (int sx = 0; sx < 2; ++sx)
                    m = fmaxf(m, bf2f(cb[((2 * py + sy) * 4 + 2 * px + sx) * 32]));
            pooled[flat] = m;
        }
        __syncthreads();
        float acc9[9];
        #pragma unroll
        for (int i = 0; i < 9; ++i) acc9[i] = bias;
        const float* pp = pooled + le * 128;
        #pragma unroll
        for (int ic = 0; ic < 32; ++ic) {
            float4 p = *(const float4*)(pp + ic * 4);
            float pv[4] = {p.x, p.y, p.z, p.w};
            float w[4];
            #pragma unroll
            for (int tap = 0; tap < 4; ++tap)
                w[tap] = wTs[(ic * 4 + tap) * 65 + oc];
            #pragma unroll
            for (int q = 0; q < 4; ++q) {
                int iy = q >> 1, ix = q & 1;
                #pragma unroll
                for (int ky = 0; ky < 2; ++ky)
                    #pragma unroll
                    for (int kx = 0; kx < 2; ++kx)
                        acc9[(iy + 1 - ky) * 3 + (ix + 1 - kx)] += pv[q] * w[ky * 2 + kx];
            }
        }
        u16* outp = feat + (size_t)(e0 + le) * FSTRIDE;
        #pragma unroll
        for (int i = 0; i < 9; ++i)
            outp[oc * 9 + i] = f2bf(fmaxf(acc9[i], 0.0f));
        if (oc == 0) outp[576] = f2bf((float)ccol[e0 + le]);
        if (oc == 1) outp[577] = f2bf((float)cobj[e0 + le]);
        if (oc >= 2 && oc < 8) outp[576 + oc] = 0;   // zero pad cols 578..583
    }
}

// ---------------- K0b: convert proj_w to bf16 [64][608], zero-padded ----
__global__ __launch_bounds__(256) void k0_cvtB(const float* __restrict__ pw,
        u16* __restrict__ pwT) {
    int idx = blockIdx.x * 256 + threadIdx.x;
    if (idx >= 64 * 608) return;
    int j = idx / 608, k = idx - j * 608;
    float v = (k < 578) ? pw[j * 578 + k] : 0.f;
    pwT[idx] = f2bf(v);
}

// ---------------- K4: proj via MFMA, LDS-free --------------------------
// Block = 256 thr (4 waves). Wave w: rows m0+w*16..+16, all 64 cols.
// A frag = direct 16B global load (A has no intra-block reuse).
// B frags = direct 16B global loads (78 KB total, L1/L2-hot).
__global__ __launch_bounds__(256) void k4_proj_mfma(const u16* __restrict__ feat,
        const u16* __restrict__ pwT, const float* __restrict__ pb,
        float* __restrict__ emb) {
    int t = threadIdx.x;
    int l = t & 63;
    int w = t >> 6;
    int m0 = blockIdx.x * 64 + w * 16;
    int col = l & 15;
    int kg = l >> 4;                          // 0..3
    const u16* arow = feat + (size_t)(m0 + col) * FSTRIDE + kg * 8;
    const u16* brow = pwT + col * 608 + kg * 8;

    f32x4 acc[4];
    #pragma unroll
    for (int i = 0; i < 4; ++i) {
        acc[i][0] = 0.f; acc[i][1] = 0.f; acc[i][2] = 0.f; acc[i][3] = 0.f;
    }

    #pragma unroll 4
    for (int k0 = 0; k0 < 608; k0 += 32) {
        bf16x8 a;
        if (k0 + kg * 8 < 584) {
            a = *(const bf16x8*)(arow + k0);
        } else {
            #pragma unroll
            for (int j = 0; j < 8; ++j) a[j] = 0;
        }
        bf16x8 b0 = *(const bf16x8*)(brow + k0);
        bf16x8 b1 = *(const bf16x8*)(brow + 16 * 608 + k0);
        bf16x8 b2 = *(const bf16x8*)(brow + 32 * 608 + k0);
        bf16x8 b3 = *(const bf16x8*)(brow + 48 * 608 + k0);
        acc[0] = __builtin_amdgcn_mfma_f32_16x16x32_bf16(a, b0, acc[0], 0, 0, 0);
        acc[1] = __builtin_amdgcn_mfma_f32_16x16x32_bf16(a, b1, acc[1], 0, 0, 0);
        acc[2] = __builtin_amdgcn_mfma_f32_16x16x32_bf16(a, b2, acc[2], 0, 0, 0);
        acc[3] = __builtin_amdgcn_mfma_f32_16x16x32_bf16(a, b3, acc[3], 0, 0, 0);
    }

    // C/D layout: col = lane&15, row = (lane>>4)*4 + reg
    #pragma unroll
    for (int nt = 0; nt < 4; ++nt) {
        float pbv = pb[nt * 16 + col];
        #pragma unroll
        for (int r = 0; r < 4; ++r) {
            int row = m0 + kg * 4 + r;
            emb[row * 64 + nt * 16 + col] = fmaxf(acc[nt][r] + pbv, 0.f);
        }
    }
}

// ---------------- K5: dir_pos deltas -> extras[b][4] --------------------
__global__ __launch_bounds__(256) void k5_extras(const int* __restrict__ frame,
        float* __restrict__ extras) {
    int b = blockIdx.x * 256 + threadIdx.x;
    int d[2]; float posy[2], posx[2];
    for (int f = 0; f < 2; ++f) {
        const int* fb = frame + (size_t)(f * BATCH + b) * 147;
        int idx = 49;
        for (int cell = 0; cell < 49; ++cell) {
            int v = fb[cell * 3];
            if (idx == 49 && v == 10) idx = cell;
        }
        if (idx < 49) {
            d[f] = fb[idx * 3 + 2] & 3;
            posy[f] = (float)(idx / 7) / 6.0f;
            posx[f] = (float)(idx % 7) / 6.0f;
        } else {
            d[f] = 0; posy[f] = 0.5f; posx[f] = 0.5f;
        }
    }
    int delta = (d[1] - d[0] + 4) & 3;
    const float ANG = (float)(2.0 * 3.14159 / 4.0);
    float angle = (float)delta * ANG;
    extras[b * 4 + 0] = sinf(angle);
    extras[b * 4 + 1] = cosf(angle);
    extras[b * 4 + 2] = posy[1] - posy[0];
    extras[b * 4 + 3] = posx[1] - posx[0];
}

// ---------------- K6: h1 GEMM (gathered A, K=132) + bias + LN + relu ----
__global__ __launch_bounds__(128) void k6_h1(
        const float* __restrict__ emb, const float* __restrict__ extras,
        const float* __restrict__ w, const float* __restrict__ bias,
        const float* __restrict__ lng, const float* __restrict__ lnb,
        float* __restrict__ out) {
    __shared__ float As[64 * 133];
    __shared__ float Bs[32 * 129];
    __shared__ float mu_s[64], rs_s[64];
    int t = threadIdx.x;
    int b0 = blockIdx.x * 64;
    {
        int r = t >> 1, half = t & 1;
        int gb = b0 + r;
        for (int kk = 0; kk < 66; ++kk) {
            int k = half * 66 + kk;
            float v;
            if (k < 64)       v = emb[gb * 64 + k];
            else if (k < 128) v = emb[(BATCH + gb) * 64 + (k - 64)];
            else              v = extras[gb * 4 + (k - 128)];
            As[r * 133 + k] = v;
        }
    }
    int tm = t >> 4, tn = t & 15;
    float acc[8][8];
    #pragma unroll
    for (int i = 0; i < 8; ++i)
        #pragma unroll
        for (int j = 0; j < 8; ++j) acc[i][j] = 0.f;

    for (int k0 = 0; k0 < 132; k0 += 32) {
        int kl = 132 - k0; if (kl > 32) kl = 32;
        __syncthreads();
        for (int i = 0; i < 32; ++i) {
            int idx = i * 128 + t;
            int j = idx >> 5, kk = idx & 31;
            Bs[kk * 129 + j] = (kk < kl) ? w[j * 132 + k0 + kk] : 0.f;
        }
        __syncthreads();
        for (int kk = 0; kk < kl; ++kk) {
            float a[8], b[8];
            #pragma unroll
            for (int i = 0; i < 8; ++i) a[i] = As[(tm * 8 + i) * 133 + k0 + kk];
            #pragma unroll
            for (int j = 0; j < 8; ++j) b[j] = Bs[kk * 129 + tn + 16 * j];
            #pragma unroll
            for (int i = 0; i < 8; ++i)
                #pragma unroll
                for (int j = 0; j < 8; ++j)
                    acc[i][j] += a[i] * b[j];
        }
    }
    __syncthreads();
    float* h = As;
    #pragma unroll
    for (int i = 0; i < 8; ++i)
        #pragma unroll
        for (int j = 0; j < 8; ++j) {
            int jj = tn + 16 * j;
            h[(tm * 8 + i) * 129 + jj] = acc[i][j] + bias[jj];
        }
    __syncthreads();
    if (t < 64) {
        float s = 0.f;
        for (int k = 0; k < 128; ++k) s += h[t * 129 + k];
        float mu = s * (1.0f / 128.0f);
        float vs = 0.f;
        for (int k = 0; k < 128; ++k) { float d = h[t * 129 + k] - mu; vs += d * d; }
        mu_s[t] = mu;
        rs_s[t] = rsqrtf(vs * (1.0f / 128.0f) + 1e-5f);
    }
    __syncthreads();
    for (int i = 0; i < 64; ++i) {
        int o = i * 128 + t;
        int r = o >> 7, j = o & 127;
        float v = (h[r * 129 + j] - mu_s[r]) * rs_s[r] * lng[j] + lnb[j];
        out[(b0 + r) * 128 + j] = fmaxf(v, 0.f);
    }
}

// ---------------- K7: h2 GEMM [32768x128]@[128->128] + relu -------------
__global__ __launch_bounds__(128) void k7_h2(
        const float* __restrict__ in, const float* __restrict__ w,
        const float* __restrict__ bias, float* __restrict__ out) {
    __shared__ float As[64 * 129];
    __shared__ float Bs[32 * 129];
    int t = threadIdx.x;
    int b0 = blockIdx.x * 64;
    {
        int r = t >> 1, half = t & 1;
        for (int kk = 0; kk < 64; ++kk) {
            int k = half * 64 + kk;
            As[r * 129 + k] = in[(b0 + r) * 128 + k];
        }
    }
    int tm = t >> 4, tn = t & 15;
    float acc[8][8];
    #pragma unroll
    for (int i = 0; i < 8; ++i)
        #pragma unroll
        for (int j = 0; j < 8; ++j) acc[i][j] = 0.f;

    for (int k0 = 0; k0 < 128; k0 += 32) {
        __syncthreads();
        for (int i = 0; i < 32; ++i) {
            int idx = i * 128 + t;
            int j = idx >> 5, kk = idx & 31;
            Bs[kk * 129 + j] = w[j * 128 + k0 + kk];
        }
        __syncthreads();
        for (int kk = 0; kk < 32; ++kk) {
            float a[8], b[8];
            #pragma unroll
            for (int i = 0; i < 8; ++i) a[i] = As[(tm * 8 + i) * 129 + k0 + kk];
            #pragma unroll
            for (int j = 0; j < 8; ++j) b[j] = Bs[kk * 129 + tn + 16 * j];
            #pragma unroll
            for (int i = 0; i < 8; ++i)
                #pragma unroll
                for (int j = 0; j < 8; ++j)
                    acc[i][j] += a[i] * b[j];
        }
    }
    #pragma unroll
    for (int i = 0; i < 8; ++i)
        #pragma unroll
        for (int j = 0; j < 8; ++j) {
            int jj = tn + 16 * j;
            out[(b0 + tm * 8 + i) * 128 + jj] = fmaxf(acc[i][j] + bias[jj], 0.f);
        }
}

// ---------------- K8: h3 [32768x128]@[128->7] ---------------------------
__global__ __launch_bounds__(256) void k8_h3(const float* __restrict__ in,
        const float* __restrict__ w, const float* __restrict__ bias,
        float* __restrict__ out) {
    __shared__ float As[64 * 129];
    int t = threadIdx.x;
    int b0 = blockIdx.x * 64;
    for (int i = 0; i < 32; ++i) {
        int idx = i * 256 + t;
        int r = idx >> 7, k = idx & 127;
        As[r * 129 + k] = in[(b0 + r) * 128 + k];
    }
    __syncthreads();
    int r = t & 63, jg = t >> 6;
    #pragma unroll
    for (int u = 0; u < 2; ++u) {
        int j = jg * 2 + u;
        if (j < 7) {
            float acc = bias[j];
            for (int k = 0; k < 128; ++k)
                acc += As[r * 129 + k] * w[j * 128 + k];
            out[(b0 + r) * 7 + j] = acc;
        }
    }
}

extern "C" void kernel_launch(void* const* d_in, const int* in_sizes, int n_in,
                              void* d_out, int out_size, void* d_ws, size_t ws_size,
                              hipStream_t stream) {
    const int*   frame = (const int*)d_in[0];
    const int*   ccol  = (const int*)d_in[1];
    const int*   cobj  = (const int*)d_in[2];
    const float* w1    = (const float*)d_in[3];
    const float* b1    = (const float*)d_in[4];
    const float* w2    = (const float*)d_in[5];
    const float* b2    = (const float*)d_in[6];
    const float* w3    = (const float*)d_in[7];
    const float* b3    = (const float*)d_in[8];
    const float* pw    = (const float*)d_in[9];
    const float* pb    = (const float*)d_in[10];
    const float* h1w   = (const float*)d_in[11];
    const float* h1b   = (const float*)d_in[12];
    const float* lng   = (const float*)d_in[13];
    const float* lnb   = (const float*)d_in[14];
    const float* h2w   = (const float*)d_in[15];
    const float* h2b   = (const float*)d_in[16];
    const float* h3w   = (const float*)d_in[17];
    const float* h3b   = (const float*)d_in[18];
    float* out = (float*)d_out;

    char* ws = (char*)d_ws;
    // [0, 64MB): c2act (bf16); after k3 dead -> emb/extras/h1out/h2out/pwT
    // [64MB, ...): pooled1 (fp32, 64MB); after k2 dead -> feat (bf16, 76.5MB)
    u16*   c2act   = (u16*)(ws + 0);
    float* pooled1 = (float*)(ws + (1ull << 26));
    u16*   feat    = (u16*)(ws + (1ull << 26));
    float* emb     = (float*)(ws + 0);                 // 16 MB
    float* extras  = (float*)(ws + 16777216);          // 512 KB
    float* h1out   = (float*)(ws + 17301504);          // 16 MB
    float* h2out   = (float*)(ws + 34078720);          // 16 MB (ends 48.5MB)
    u16*   pwT     = (u16*)(ws + 52428800);            // 78 KB @ 50MB (after k3)

    k1_conv1<<<4096, 256, 0, stream>>>(frame, w1, b1, pooled1);
    k2_conv2<<<4096, 256, 0, stream>>>(pooled1, w2, b2, c2act);
    k3_conv3<<<2048, 256, 0, stream>>>(c2act, w3, b3, ccol, cobj, feat);
    k0_cvtB<<<152, 256, 0, stream>>>(pw, pwT);
    k4_proj_mfma<<<1024, 256, 0, stream>>>(feat, pwT, pb, emb);
    k5_extras<<<128, 256, 0, stream>>>(frame, extras);
    k6_h1<<<512, 128, 0, stream>>>(emb, extras, h1w, h1b, lng, lnb, h1out);
    k7_h2<<<512, 128, 0, stream>>>(h1out, h2w, h2b, h2out);
    k8_h3<<<512, 256, 0, stream>>>(h2out, h3w, h3b, out);
}

// Round 4
// 352.455 us; speedup vs baseline: 2.6280x; 1.3501x over previous
//
#include <hip/hip_runtime.h>
#include <hip/hip_bf16.h>

#define BATCH 32768
#define NELEM 65536   // 2 * BATCH
#define FSTRIDE 584   // feat row stride (578 cols + 6 zeroed pad cols)

typedef unsigned short u16;
typedef unsigned int u32;
typedef __attribute__((ext_vector_type(8))) short bf16x8;
typedef __attribute__((ext_vector_type(4))) float f32x4;

__device__ __forceinline__ float bf2f(u16 u) {
    union { u32 u; float f; } c; c.u = ((u32)u) << 16; return c.f;
}
__device__ __forceinline__ u16 f2bf(float f) {
    union { float f; u32 u; } c; c.f = f;
    u32 x = c.u;
    u32 r = (x + 0x7fffu + ((x >> 16) & 1u)) >> 16;  // RNE
    return (u16)r;
}

// ---------------- K0: weight prep (all bf16 reorders in one launch) ----
// pwT: [64][608] zero-padded proj_w
// w2r: [oc32][k=tap*16+ic]  from w2 [oc][ic][ky][kx]
// w3r: [oc64][k=tap*32+ic]  from w3 [oc][ic][ky][kx]
__global__ __launch_bounds__(256) void k0_prep(const float* __restrict__ pw,
        const float* __restrict__ w2, const float* __restrict__ w3,
        u16* __restrict__ pwT, u16* __restrict__ w2r, u16* __restrict__ w3r) {
    int idx = blockIdx.x * 256 + threadIdx.x;
    if (idx < 64 * 608) {
        int j = idx / 608, k = idx - j * 608;
        pwT[idx] = f2bf(k < 578 ? pw[j * 578 + k] : 0.f);
    } else if (idx < 64 * 608 + 2048) {
        int i = idx - 64 * 608;
        int oc = i >> 6, rem = i & 63, tap = rem >> 4, ic = rem & 15;
        w2r[i] = f2bf(w2[oc * 64 + ic * 4 + tap]);
    } else if (idx < 64 * 608 + 2048 + 8192) {
        int i = idx - (64 * 608 + 2048);
        int oc = i >> 7, rem = i & 127, tap = rem >> 5, ic = rem & 31;
        w3r[i] = f2bf(w3[oc * 128 + ic * 4 + tap]);
    }
}

// ---------------- K1: conv1 (pad1,k2) + relu + maxpool2 -> bf16 --------
// thread = (elem, pooled pos). out: pooled1b[elem][pos(16)][ch(16)] bf16
__global__ __launch_bounds__(256) void k1_conv1(const int* __restrict__ frame,
        const float* __restrict__ w1, const float* __restrict__ b1,
        u16* __restrict__ pooled1b) {
    int t = blockIdx.x * 256 + threadIdx.x;
    int elem = t >> 4;
    int pos = t & 15;
    int py = pos >> 2, px = pos & 3;
    const int* fb = frame + elem * 147;
    float patch[3][3][3];  // [c][dy][dx]
    int iy0 = 2 * py - 1, ix0 = 2 * px - 1;
    #pragma unroll
    for (int dy = 0; dy < 3; ++dy) {
        int iy = iy0 + dy;
        #pragma unroll
        for (int dx = 0; dx < 3; ++dx) {
            int ix = ix0 + dx;
            bool ok = (iy >= 0 && iy < 7 && ix >= 0 && ix < 7);
            int base = (iy * 7 + ix) * 3;
            #pragma unroll
            for (int c = 0; c < 3; ++c)
                patch[c][dy][dx] = ok ? (float)fb[base + c] : 0.0f;
        }
    }
    union { u16 s[16]; uint4 q[2]; } ob;
    for (int oc = 0; oc < 16; ++oc) {
        float bias = b1[oc];
        float m = 0.0f;
        #pragma unroll
        for (int sy = 0; sy < 2; ++sy)
        #pragma unroll
        for (int sx = 0; sx < 2; ++sx) {
            float acc = bias;
            #pragma unroll
            for (int ic = 0; ic < 3; ++ic)
            #pragma unroll
            for (int ky = 0; ky < 2; ++ky)
            #pragma unroll
            for (int kx = 0; kx < 2; ++kx)
                acc += patch[ic][sy + ky][sx + kx] * w1[oc * 12 + ic * 4 + ky * 2 + kx];
            acc = fmaxf(acc, 0.0f);
            m = fmaxf(m, acc);
        }
        ob.s[oc] = f2bf(m);
    }
    uint4* outp = (uint4*)(pooled1b + elem * 256 + pos * 16);
    outp[0] = ob.q[0];
    outp[1] = ob.q[1];
}

// ---------------- K2: conv2+relu+maxpool fused via MFMA, LDS-free ------
// Implicit GEMM: M=(elem,pos16), N=32, K=64 (tap*16+ic).
// A frag = 16B direct load from pooled1b. B hoisted in regs.
// Pool 2x2 in-register: reg-pair max + __shfl_xor(16). Writes pooled2 only.
#define K2_WAVES 4096
__global__ __launch_bounds__(256) void k2_conv2_mfma(const u16* __restrict__ pooled1b,
        const u16* __restrict__ w2r, const float* __restrict__ b2,
        u16* __restrict__ pooled2) {
    int t = threadIdx.x;
    int l = t & 63;
    int col = l & 15;
    int kg = l >> 4;
    int wv = (blockIdx.x * 256 + t) >> 6;

    bf16x8 bfrag[2][2];
    #pragma unroll
    for (int s = 0; s < 2; ++s)
        #pragma unroll
        for (int nt = 0; nt < 2; ++nt)
            bfrag[s][nt] = *(const bf16x8*)(w2r + (nt * 16 + col) * 64 + s * 32 + kg * 8);
    float bias[2] = { b2[col], b2[16 + col] };

    // A addressing (loop-invariant): A-row pos = l&15 -> (oy,ox)
    int oy = col >> 2, ox = col & 3;
    int aoff[2]; bool aok[2];
    #pragma unroll
    for (int s = 0; s < 2; ++s) {
        int tap = 2 * s + (kg >> 1);
        int ky = tap >> 1, kx = tap & 1;
        int iy = oy - 1 + ky, ix = ox - 1 + kx;
        aok[s] = (iy >= 0 && ix >= 0);       // iy,ix <= 3 always
        aoff[s] = (iy * 4 + ix) * 16 + (kg & 1) * 8;
    }

    for (int e = wv; e < NELEM; e += K2_WAVES) {
        const u16* pbase = pooled1b + e * 256;
        bf16x8 a0 = {0,0,0,0,0,0,0,0}, a1 = {0,0,0,0,0,0,0,0};
        if (aok[0]) a0 = *(const bf16x8*)(pbase + aoff[0]);
        if (aok[1]) a1 = *(const bf16x8*)(pbase + aoff[1]);
        f32x4 acc0 = {0.f,0.f,0.f,0.f}, acc1 = {0.f,0.f,0.f,0.f};
        acc0 = __builtin_amdgcn_mfma_f32_16x16x32_bf16(a0, bfrag[0][0], acc0, 0, 0, 0);
        acc1 = __builtin_amdgcn_mfma_f32_16x16x32_bf16(a0, bfrag[0][1], acc1, 0, 0, 0);
        acc0 = __builtin_amdgcn_mfma_f32_16x16x32_bf16(a1, bfrag[1][0], acc0, 0, 0, 0);
        acc1 = __builtin_amdgcn_mfma_f32_16x16x32_bf16(a1, bfrag[1][1], acc1, 0, 0, 0);
        // C rows = pos = kg*4+r; kg=(py,sy), r=(px,sx). relu then pool.
        #pragma unroll
        for (int nt = 0; nt < 2; ++nt) {
            f32x4 acc = nt ? acc1 : acc0;
            float b = bias[nt];
            float m0 = fmaxf(fmaxf(acc[0] + b, 0.f), fmaxf(acc[1] + b, 0.f)); // px=0
            float m1 = fmaxf(fmaxf(acc[2] + b, 0.f), fmaxf(acc[3] + b, 0.f)); // px=1
            float p0 = fmaxf(m0, __shfl_xor(m0, 16, 64));  // max over sy
            float p1 = fmaxf(m1, __shfl_xor(m1, 16, 64));
            if ((kg & 1) == 0) {
                int q = (kg >> 1) * 2;                     // q = py*2+px
                u16* op = pooled2 + e * 128 + nt * 16 + col;
                op[q * 32]       = f2bf(p0);
                op[(q + 1) * 32] = f2bf(p1);
            }
        }
    }
}

// ---------------- K3: conv3+relu via MFMA, LDS-free --------------------
// Implicit GEMM: M=(elem,pos9)=589824, N=64, K=128 (tap*32+ic).
// A frag = 16B direct load from pooled2 (OOB taps -> zero). B hoisted (64 VGPRs).
#define K3_WAVES 4096
__global__ __launch_bounds__(256) void k3_conv3_mfma(const u16* __restrict__ pooled2,
        const u16* __restrict__ w3r, const float* __restrict__ b3,
        u16* __restrict__ feat) {
    int t = threadIdx.x;
    int l = t & 63;
    int col = l & 15;
    int kg = l >> 4;
    int wv = (blockIdx.x * 256 + t) >> 6;
    const int NTILE = (NELEM * 9) / 16;  // 36864

    bf16x8 bfrag[4][4];
    #pragma unroll
    for (int s = 0; s < 4; ++s)
        #pragma unroll
        for (int nt = 0; nt < 4; ++nt)
            bfrag[s][nt] = *(const bf16x8*)(w3r + (nt * 16 + col) * 128 + s * 32 + kg * 8);
    float bias[4];
    #pragma unroll
    for (int nt = 0; nt < 4; ++nt) bias[nt] = b3[nt * 16 + col];

    for (int mt = wv; mt < NTILE; mt += K3_WAVES) {
        int m0 = mt * 16;
        // A-row for this lane: m -> (elem, p); p -> (oy,ox)
        int m = m0 + col;
        u32 elem = (u32)(((unsigned long long)(u32)m * 954437177ull) >> 33); // m/9
        int p = m - (int)elem * 9;
        int oy = (p * 86) >> 8;   // p/3 for p<9
        int ox = p - 3 * oy;
        const u16* pbase = pooled2 + (size_t)elem * 128 + kg * 8;
        f32x4 acc[4];
        #pragma unroll
        for (int nt = 0; nt < 4; ++nt) {
            acc[nt][0] = 0.f; acc[nt][1] = 0.f; acc[nt][2] = 0.f; acc[nt][3] = 0.f;
        }
        #pragma unroll
        for (int s = 0; s < 4; ++s) {
            int ky = s >> 1, kx = s & 1;
            int iy = oy - 1 + ky, ix = ox - 1 + kx;
            bf16x8 a = {0,0,0,0,0,0,0,0};
            if (iy >= 0 && iy <= 1 && ix >= 0 && ix <= 1)
                a = *(const bf16x8*)(pbase + (iy * 2 + ix) * 32);
            #pragma unroll
            for (int nt = 0; nt < 4; ++nt)
                acc[nt] = __builtin_amdgcn_mfma_f32_16x16x32_bf16(a, bfrag[s][nt], acc[nt], 0, 0, 0);
        }
        // epilogue: C rows = m0 + kg*4 + r, cols oc = nt*16+col
        #pragma unroll
        for (int r = 0; r < 4; ++r) {
            int mr = m0 + kg * 4 + r;
            u32 er = (u32)(((unsigned long long)(u32)mr * 954437177ull) >> 33);
            int pr = mr - (int)er * 9;
            u16* fb = feat + (size_t)er * FSTRIDE + pr;
            #pragma unroll
            for (int nt = 0; nt < 4; ++nt)
                fb[(nt * 16 + col) * 9] = f2bf(fmaxf(acc[nt][r] + bias[nt], 0.f));
        }
    }
}

// ---------------- K3b: feat tail cols 576..583 (carried + zero pad) ----
__global__ __launch_bounds__(256) void k3_tail(const int* __restrict__ ccol,
        const int* __restrict__ cobj, u16* __restrict__ feat) {
    int e = blockIdx.x * 256 + threadIdx.x;
    union { u16 s[8]; uint4 q; } b;
    b.s[0] = f2bf((float)ccol[e]);
    b.s[1] = f2bf((float)cobj[e]);
    #pragma unroll
    for (int i = 2; i < 8; ++i) b.s[i] = 0;
    *(uint4*)(feat + (size_t)e * FSTRIDE + 576) = b.q;
}

// ---------------- K4: proj via MFMA, LDS-free --------------------------
__global__ __launch_bounds__(256) void k4_proj_mfma(const u16* __restrict__ feat,
        const u16* __restrict__ pwT, const float* __restrict__ pb,
        float* __restrict__ emb) {
    int t = threadIdx.x;
    int l = t & 63;
    int w = t >> 6;
    int m0 = blockIdx.x * 64 + w * 16;
    int col = l & 15;
    int kg = l >> 4;
    const u16* arow = feat + (size_t)(m0 + col) * FSTRIDE + kg * 8;
    const u16* brow = pwT + col * 608 + kg * 8;

    f32x4 acc[4];
    #pragma unroll
    for (int i = 0; i < 4; ++i) {
        acc[i][0] = 0.f; acc[i][1] = 0.f; acc[i][2] = 0.f; acc[i][3] = 0.f;
    }

    #pragma unroll 4
    for (int k0 = 0; k0 < 608; k0 += 32) {
        bf16x8 a;
        if (k0 + kg * 8 < 584) {
            a = *(const bf16x8*)(arow + k0);
        } else {
            #pragma unroll
            for (int j = 0; j < 8; ++j) a[j] = 0;
        }
        bf16x8 b0 = *(const bf16x8*)(brow + k0);
        bf16x8 b1 = *(const bf16x8*)(brow + 16 * 608 + k0);
        bf16x8 b2 = *(const bf16x8*)(brow + 32 * 608 + k0);
        bf16x8 b3 = *(const bf16x8*)(brow + 48 * 608 + k0);
        acc[0] = __builtin_amdgcn_mfma_f32_16x16x32_bf16(a, b0, acc[0], 0, 0, 0);
        acc[1] = __builtin_amdgcn_mfma_f32_16x16x32_bf16(a, b1, acc[1], 0, 0, 0);
        acc[2] = __builtin_amdgcn_mfma_f32_16x16x32_bf16(a, b2, acc[2], 0, 0, 0);
        acc[3] = __builtin_amdgcn_mfma_f32_16x16x32_bf16(a, b3, acc[3], 0, 0, 0);
    }

    #pragma unroll
    for (int nt = 0; nt < 4; ++nt) {
        float pbv = pb[nt * 16 + col];
        #pragma unroll
        for (int r = 0; r < 4; ++r) {
            int row = m0 + kg * 4 + r;
            emb[row * 64 + nt * 16 + col] = fmaxf(acc[nt][r] + pbv, 0.f);
        }
    }
}

// ---------------- K5: dir_pos deltas -> extras[b][4] --------------------
__global__ __launch_bounds__(256) void k5_extras(const int* __restrict__ frame,
        float* __restrict__ extras) {
    int b = blockIdx.x * 256 + threadIdx.x;
    int d[2]; float posy[2], posx[2];
    for (int f = 0; f < 2; ++f) {
        const int* fb = frame + (size_t)(f * BATCH + b) * 147;
        int idx = 49;
        for (int cell = 0; cell < 49; ++cell) {
            int v = fb[cell * 3];
            if (idx == 49 && v == 10) idx = cell;
        }
        if (idx < 49) {
            d[f] = fb[idx * 3 + 2] & 3;
            posy[f] = (float)(idx / 7) / 6.0f;
            posx[f] = (float)(idx % 7) / 6.0f;
        } else {
            d[f] = 0; posy[f] = 0.5f; posx[f] = 0.5f;
        }
    }
    int delta = (d[1] - d[0] + 4) & 3;
    const float ANG = (float)(2.0 * 3.14159 / 4.0);
    float angle = (float)delta * ANG;
    extras[b * 4 + 0] = sinf(angle);
    extras[b * 4 + 1] = cosf(angle);
    extras[b * 4 + 2] = posy[1] - posy[0];
    extras[b * 4 + 3] = posx[1] - posx[0];
}

// ---------------- K6: h1 GEMM (gathered A, K=132) + bias + LN + relu ----
__global__ __launch_bounds__(128) void k6_h1(
        const float* __restrict__ emb, const float* __restrict__ extras,
        const float* __restrict__ w, const float* __restrict__ bias,
        const float* __restrict__ lng, const float* __restrict__ lnb,
        float* __restrict__ out) {
    __shared__ float As[64 * 133];
    __shared__ float Bs[32 * 129];
    __shared__ float mu_s[64], rs_s[64];
    int t = threadIdx.x;
    int b0 = blockIdx.x * 64;
    {
        int r = t >> 1, half = t & 1;
        int gb = b0 + r;
        for (int kk = 0; kk < 66; ++kk) {
            int k = half * 66 + kk;
            float v;
            if (k < 64)       v = emb[gb * 64 + k];
            else if (k < 128) v = emb[(BATCH + gb) * 64 + (k - 64)];
            else              v = extras[gb * 4 + (k - 128)];
            As[r * 133 + k] = v;
        }
    }
    int tm = t >> 4, tn = t & 15;
    float acc[8][8];
    #pragma unroll
    for (int i = 0; i < 8; ++i)
        #pragma unroll
        for (int j = 0; j < 8; ++j) acc[i][j] = 0.f;

    for (int k0 = 0; k0 < 132; k0 += 32) {
        int kl = 132 - k0; if (kl > 32) kl = 32;
        __syncthreads();
        for (int i = 0; i < 32; ++i) {
            int idx = i * 128 + t;
            int j = idx >> 5, kk = idx & 31;
            Bs[kk * 129 + j] = (kk < kl) ? w[j * 132 + k0 + kk] : 0.f;
        }
        __syncthreads();
        for (int kk = 0; kk < kl; ++kk) {
            float a[8], b[8];
            #pragma unroll
            for (int i = 0; i < 8; ++i) a[i] = As[(tm * 8 + i) * 133 + k0 + kk];
            #pragma unroll
            for (int j = 0; j < 8; ++j) b[j] = Bs[kk * 129 + tn + 16 * j];
            #pragma unroll
            for (int i = 0; i < 8; ++i)
                #pragma unroll
                for (int j = 0; j < 8; ++j)
                    acc[i][j] += a[i] * b[j];
        }
    }
    __syncthreads();
    float* h = As;
    #pragma unroll
    for (int i = 0; i < 8; ++i)
        #pragma unroll
        for (int j = 0; j < 8; ++j) {
            int jj = tn + 16 * j;
            h[(tm * 8 + i) * 129 + jj] = acc[i][j] + bias[jj];
        }
    __syncthreads();
    if (t < 64) {
        float s = 0.f;
        for (int k = 0; k < 128; ++k) s += h[t * 129 + k];
        float mu = s * (1.0f / 128.0f);
        float vs = 0.f;
        for (int k = 0; k < 128; ++k) { float d = h[t * 129 + k] - mu; vs += d * d; }
        mu_s[t] = mu;
        rs_s[t] = rsqrtf(vs * (1.0f / 128.0f) + 1e-5f);
    }
    __syncthreads();
    for (int i = 0; i < 64; ++i) {
        int o = i * 128 + t;
        int r = o >> 7, j = o & 127;
        float v = (h[r * 129 + j] - mu_s[r]) * rs_s[r] * lng[j] + lnb[j];
        out[(b0 + r) * 128 + j] = fmaxf(v, 0.f);
    }
}

// ---------------- K7: h2 GEMM [32768x128]@[128->128] + relu -------------
__global__ __launch_bounds__(128) void k7_h2(
        const float* __restrict__ in, const float* __restrict__ w,
        const float* __restrict__ bias, float* __restrict__ out) {
    __shared__ float As[64 * 129];
    __shared__ float Bs[32 * 129];
    int t = threadIdx.x;
    int b0 = blockIdx.x * 64;
    {
        int r = t >> 1, half = t & 1;
        for (int kk = 0; kk < 64; ++kk) {
            int k = half * 64 + kk;
            As[r * 129 + k] = in[(b0 + r) * 128 + k];
        }
    }
    int tm = t >> 4, tn = t & 15;
    float acc[8][8];
    #pragma unroll
    for (int i = 0; i < 8; ++i)
        #pragma unroll
        for (int j = 0; j < 8; ++j) acc[i][j] = 0.f;

    for (int k0 = 0; k0 < 128; k0 += 32) {
        __syncthreads();
        for (int i = 0; i < 32; ++i) {
            int idx = i * 128 + t;
            int j = idx >> 5, kk = idx & 31;
            Bs[kk * 129 + j] = w[j * 128 + k0 + kk];
        }
        __syncthreads();
        for (int kk = 0; kk < 32; ++kk) {
            float a[8], b[8];
            #pragma unroll
            for (int i = 0; i < 8; ++i) a[i] = As[(tm * 8 + i) * 129 + k0 + kk];
            #pragma unroll
            for (int j = 0; j < 8; ++j) b[j] = Bs[kk * 129 + tn + 16 * j];
            #pragma unroll
            for (int i = 0; i < 8; ++i)
                #pragma unroll
                for (int j = 0; j < 8; ++j)
                    acc[i][j] += a[i] * b[j];
        }
    }
    #pragma unroll
    for (int i = 0; i < 8; ++i)
        #pragma unroll
        for (int j = 0; j < 8; ++j) {
            int jj = tn + 16 * j;
            out[(b0 + tm * 8 + i) * 128 + jj] = fmaxf(acc[i][j] + bias[jj], 0.f);
        }
}

// ---------------- K8: h3 [32768x128]@[128->7] ---------------------------
__global__ __launch_bounds__(256) void k8_h3(const float* __restrict__ in,
        const float* __restrict__ w, const float* __restrict__ bias,
        float* __restrict__ out) {
    __shared__ float As[64 * 129];
    int t = threadIdx.x;
    int b0 = blockIdx.x * 64;
    for (int i = 0; i < 32; ++i) {
        int idx = i * 256 + t;
        int r = idx >> 7, k = idx & 127;
        As[r * 129 + k] = in[(b0 + r) * 128 + k];
    }
    __syncthreads();
    int r = t & 63, jg = t >> 6;
    #pragma unroll
    for (int u = 0; u < 2; ++u) {
        int j = jg * 2 + u;
        if (j < 7) {
            float acc = bias[j];
            for (int k = 0; k < 128; ++k)
                acc += As[r * 129 + k] * w[j * 128 + k];
            out[(b0 + r) * 7 + j] = acc;
        }
    }
}

extern "C" void kernel_launch(void* const* d_in, const int* in_sizes, int n_in,
                              void* d_out, int out_size, void* d_ws, size_t ws_size,
                              hipStream_t stream) {
    const int*   frame = (const int*)d_in[0];
    const int*   ccol  = (const int*)d_in[1];
    const int*   cobj  = (const int*)d_in[2];
    const float* w1    = (const float*)d_in[3];
    const float* b1    = (const float*)d_in[4];
    const float* w2    = (const float*)d_in[5];
    const float* b2    = (const float*)d_in[6];
    const float* w3    = (const float*)d_in[7];
    const float* b3    = (const float*)d_in[8];
    const float* pw    = (const float*)d_in[9];
    const float* pb    = (const float*)d_in[10];
    const float* h1w   = (const float*)d_in[11];
    const float* h1b   = (const float*)d_in[12];
    const float* lng   = (const float*)d_in[13];
    const float* lnb   = (const float*)d_in[14];
    const float* h2w   = (const float*)d_in[15];
    const float* h2b   = (const float*)d_in[16];
    const float* h3w   = (const float*)d_in[17];
    const float* h3b   = (const float*)d_in[18];
    float* out = (float*)d_out;

    char* ws = (char*)d_ws;
    // Region A [0,32MB): pooled1b (k1->k2); then emb (k4->k6) + extras (k5->k6)
    // Region B [32MB,48MB): pooled2 (k2->k3); then h1out (k6->k7)
    // Region C [48MB,~121MB): feat (k3->k4); then h2out (k7->k8)
    // Region D [126MB,...): pwT / w2r / w3r (k0->k4)
    u16*   pooled1b = (u16*)(ws + 0);                    // 32 MB
    float* emb      = (float*)(ws + 0);                  // 16 MB (after k2)
    float* extras   = (float*)(ws + 17825792);           // 512 KB
    u16*   pooled2  = (u16*)(ws + 33554432);             // 16 MB
    float* h1out    = (float*)(ws + 33554432);           // 16 MB (after k3)
    u16*   feat     = (u16*)(ws + 50331648);             // 76.5 MB
    float* h2out    = (float*)(ws + 50331648);           // 16 MB (after k4)
    u16*   pwT      = (u16*)(ws + 132120576);            // 77824 B
    u16*   w2r      = (u16*)(ws + 132120576 + 131072);   // 4096 B
    u16*   w3r      = (u16*)(ws + 132120576 + 139264);   // 16384 B

    k0_prep<<<193, 256, 0, stream>>>(pw, w2, w3, pwT, w2r, w3r);
    k1_conv1<<<4096, 256, 0, stream>>>(frame, w1, b1, pooled1b);
    k2_conv2_mfma<<<1024, 256, 0, stream>>>(pooled1b, w2r, b2, pooled2);
    k3_conv3_mfma<<<1024, 256, 0, stream>>>(pooled2, w3r, b3, feat);
    k3_tail<<<256, 256, 0, stream>>>(ccol, cobj, feat);
    k4_proj_mfma<<<1024, 256, 0, stream>>>(feat, pwT, pb, emb);
    k5_extras<<<128, 256, 0, stream>>>(frame, extras);
    k6_h1<<<512, 128, 0, stream>>>(emb, extras, h1w, h1b, lng, lnb, h1out);
    k7_h2<<<512, 128, 0, stream>>>(h1out, h2w, h2b, h2out);
    k8_h3<<<512, 256, 0, stream>>>(h2out, h3w, h3b, out);
}

// Round 7
// 343.180 us; speedup vs baseline: 2.6990x; 1.0270x over previous
//
#include <hip/hip_runtime.h>
#include <hip/hip_bf16.h>

#define BATCH 32768
#define NELEM 65536   // 2 * BATCH
#define FSTRIDE 584   // feat row stride (578 cols + 6 zeroed pad cols)

typedef unsigned short u16;
typedef unsigned int u32;
typedef __attribute__((ext_vector_type(8))) short bf16x8;
typedef __attribute__((ext_vector_type(4))) float f32x4;

__device__ __forceinline__ float bf2f(u16 u) {
    union { u32 u; float f; } c; c.u = ((u32)u) << 16; return c.f;
}
__device__ __forceinline__ u16 f2bf(float f) {
    union { float f; u32 u; } c; c.f = f;
    u32 x = c.u;
    u32 r = (x + 0x7fffu + ((x >> 16) & 1u)) >> 16;  // RNE
    return (u16)r;
}

// ---------------- K0: weight prep (bf16 reorders, conv/proj only) ------
// pwT: [64][608] zero-padded proj_w
// w2r: [oc32][k=tap*16+ic]   from w2 [oc][ic][ky][kx]
// w3r: [oc64][k=tap*32+ic]   from w3 [oc][ic][ky][kx]
__global__ __launch_bounds__(256) void k0_prep(const float* __restrict__ pw,
        const float* __restrict__ w2, const float* __restrict__ w3,
        u16* __restrict__ pwT, u16* __restrict__ w2r, u16* __restrict__ w3r) {
    int idx = blockIdx.x * 256 + threadIdx.x;
    if (idx < 38912) {
        int j = idx / 608, k = idx - j * 608;
        pwT[idx] = f2bf(k < 578 ? pw[j * 578 + k] : 0.f);
    } else if (idx < 40960) {
        int i = idx - 38912;
        int oc = i >> 6, rem = i & 63, tap = rem >> 4, ic = rem & 15;
        w2r[i] = f2bf(w2[oc * 64 + ic * 4 + tap]);
    } else if (idx < 49152) {
        int i = idx - 40960;
        int oc = i >> 7, rem = i & 127, tap = rem >> 5, ic = rem & 31;
        w3r[i] = f2bf(w3[oc * 128 + ic * 4 + tap]);
    }
}

// ---------------- K1: conv1 (pad1,k2) + relu + maxpool2 -> bf16 --------
// Block = 4 elems. Frame staged+converted in LDS once. 64 thr/elem:
// thread = conv pos (8x8), 12 MAC/oc, pool via shfl_xor(1)/(8).
__global__ __launch_bounds__(256) void k1_conv1(const int* __restrict__ frame,
        const float* __restrict__ w1, const float* __restrict__ b1,
        u16* __restrict__ pooled1b) {
    __shared__ float fr[4][160];
    int t = threadIdx.x;
    int le = t >> 6, l = t & 63;
    int e = blockIdx.x * 4 + le;
    #pragma unroll
    for (int i = 0; i < 3; ++i) {
        int off = i * 64 + l;
        if (off < 147) fr[le][off] = (float)frame[e * 147 + off];
    }
    __syncthreads();
    int pyc = l >> 3, pxc = l & 7;
    float p[2][2][3];
    #pragma unroll
    for (int ky = 0; ky < 2; ++ky) {
        int y = pyc - 1 + ky;
        #pragma unroll
        for (int kx = 0; kx < 2; ++kx) {
            int x = pxc - 1 + kx;
            bool ok = (y >= 0 && y < 7 && x >= 0 && x < 7);
            int base = (y * 7 + x) * 3;
            #pragma unroll
            for (int c = 0; c < 3; ++c)
                p[ky][kx][c] = ok ? fr[le][base + c] : 0.f;
        }
    }
    union { u16 s[16]; uint4 q[2]; } ob;
    #pragma unroll
    for (int oc = 0; oc < 16; ++oc) {
        float acc = b1[oc];
        #pragma unroll
        for (int ic = 0; ic < 3; ++ic)
            #pragma unroll
            for (int ky = 0; ky < 2; ++ky)
                #pragma unroll
                for (int kx = 0; kx < 2; ++kx)
                    acc += p[ky][kx][ic] * w1[oc * 12 + ic * 4 + ky * 2 + kx];
        acc = fmaxf(acc, 0.f);                       // relu BEFORE pool
        acc = fmaxf(acc, __shfl_xor(acc, 1, 64));    // max over px pair
        acc = fmaxf(acc, __shfl_xor(acc, 8, 64));    // max over py pair
        ob.s[oc] = f2bf(acc);
    }
    if (((pyc | pxc) & 1) == 0) {
        int pos = (pyc >> 1) * 4 + (pxc >> 1);
        uint4* outp = (uint4*)(pooled1b + e * 256 + pos * 16);
        outp[0] = ob.q[0];
        outp[1] = ob.q[1];
    }
}

// ---------------- K2: conv2+relu+maxpool fused via MFMA, LDS-free ------
#define K2_WAVES 4096
__global__ __launch_bounds__(256) void k2_conv2_mfma(const u16* __restrict__ pooled1b,
        const u16* __restrict__ w2r, const float* __restrict__ b2,
        u16* __restrict__ pooled2) {
    int t = threadIdx.x;
    int l = t & 63;
    int col = l & 15;
    int kg = l >> 4;
    int wv = (blockIdx.x * 256 + t) >> 6;

    bf16x8 bfrag[2][2];
    #pragma unroll
    for (int s = 0; s < 2; ++s)
        #pragma unroll
        for (int nt = 0; nt < 2; ++nt)
            bfrag[s][nt] = *(const bf16x8*)(w2r + (nt * 16 + col) * 64 + s * 32 + kg * 8);
    float bias[2] = { b2[col], b2[16 + col] };

    int oy = col >> 2, ox = col & 3;
    int aoff[2]; bool aok[2];
    #pragma unroll
    for (int s = 0; s < 2; ++s) {
        int tap = 2 * s + (kg >> 1);
        int ky = tap >> 1, kx = tap & 1;
        int iy = oy - 1 + ky, ix = ox - 1 + kx;
        aok[s] = (iy >= 0 && ix >= 0);
        aoff[s] = (iy * 4 + ix) * 16 + (kg & 1) * 8;
    }

    for (int e = wv; e < NELEM; e += K2_WAVES) {
        const u16* pbase = pooled1b + e * 256;
        bf16x8 a0 = {0,0,0,0,0,0,0,0}, a1 = {0,0,0,0,0,0,0,0};
        if (aok[0]) a0 = *(const bf16x8*)(pbase + aoff[0]);
        if (aok[1]) a1 = *(const bf16x8*)(pbase + aoff[1]);
        f32x4 acc0 = {0.f,0.f,0.f,0.f}, acc1 = {0.f,0.f,0.f,0.f};
        acc0 = __builtin_amdgcn_mfma_f32_16x16x32_bf16(a0, bfrag[0][0], acc0, 0, 0, 0);
        acc1 = __builtin_amdgcn_mfma_f32_16x16x32_bf16(a0, bfrag[0][1], acc1, 0, 0, 0);
        acc0 = __builtin_amdgcn_mfma_f32_16x16x32_bf16(a1, bfrag[1][0], acc0, 0, 0, 0);
        acc1 = __builtin_amdgcn_mfma_f32_16x16x32_bf16(a1, bfrag[1][1], acc1, 0, 0, 0);
        #pragma unroll
        for (int nt = 0; nt < 2; ++nt) {
            f32x4 acc = nt ? acc1 : acc0;
            float b = bias[nt];
            float m0 = fmaxf(fmaxf(acc[0] + b, 0.f), fmaxf(acc[1] + b, 0.f));
            float m1 = fmaxf(fmaxf(acc[2] + b, 0.f), fmaxf(acc[3] + b, 0.f));
            float p0 = fmaxf(m0, __shfl_xor(m0, 16, 64));
            float p1 = fmaxf(m1, __shfl_xor(m1, 16, 64));
            if ((kg & 1) == 0) {
                int q = (kg >> 1) * 2;
                u16* op = pooled2 + e * 128 + nt * 16 + col;
                op[q * 32]       = f2bf(p0);
                op[(q + 1) * 32] = f2bf(p1);
            }
        }
    }
}

// ---------------- K3: conv3+relu via MFMA, LDS-free --------------------
#define K3_WAVES 4096
__global__ __launch_bounds__(256) void k3_conv3_mfma(const u16* __restrict__ pooled2,
        const u16* __restrict__ w3r, const float* __restrict__ b3,
        u16* __restrict__ feat) {
    int t = threadIdx.x;
    int l = t & 63;
    int col = l & 15;
    int kg = l >> 4;
    int wv = (blockIdx.x * 256 + t) >> 6;
    const int NTILE = (NELEM * 9) / 16;  // 36864

    bf16x8 bfrag[4][4];
    #pragma unroll
    for (int s = 0; s < 4; ++s)
        #pragma unroll
        for (int nt = 0; nt < 4; ++nt)
            bfrag[s][nt] = *(const bf16x8*)(w3r + (nt * 16 + col) * 128 + s * 32 + kg * 8);
    float bias[4];
    #pragma unroll
    for (int nt = 0; nt < 4; ++nt) bias[nt] = b3[nt * 16 + col];

    for (int mt = wv; mt < NTILE; mt += K3_WAVES) {
        int m0 = mt * 16;
        int m = m0 + col;
        u32 elem = (u32)(((unsigned long long)(u32)m * 954437177ull) >> 33); // m/9
        int p = m - (int)elem * 9;
        int oy = (p * 86) >> 8;
        int ox = p - 3 * oy;
        const u16* pbase = pooled2 + (size_t)elem * 128 + kg * 8;
        f32x4 acc[4];
        #pragma unroll
        for (int nt = 0; nt < 4; ++nt) {
            acc[nt][0] = 0.f; acc[nt][1] = 0.f; acc[nt][2] = 0.f; acc[nt][3] = 0.f;
        }
        #pragma unroll
        for (int s = 0; s < 4; ++s) {
            int ky = s >> 1, kx = s & 1;
            int iy = oy - 1 + ky, ix = ox - 1 + kx;
            bf16x8 a = {0,0,0,0,0,0,0,0};
            if (iy >= 0 && iy <= 1 && ix >= 0 && ix <= 1)
                a = *(const bf16x8*)(pbase + (iy * 2 + ix) * 32);
            #pragma unroll
            for (int nt = 0; nt < 4; ++nt)
                acc[nt] = __builtin_amdgcn_mfma_f32_16x16x32_bf16(a, bfrag[s][nt], acc[nt], 0, 0, 0);
        }
        #pragma unroll
        for (int r = 0; r < 4; ++r) {
            int mr = m0 + kg * 4 + r;
            u32 er = (u32)(((unsigned long long)(u32)mr * 954437177ull) >> 33);
            int pr = mr - (int)er * 9;
            u16* fb = feat + (size_t)er * FSTRIDE + pr;
            #pragma unroll
            for (int nt = 0; nt < 4; ++nt)
                fb[(nt * 16 + col) * 9] = f2bf(fmaxf(acc[nt][r] + bias[nt], 0.f));
        }
    }
}

// ---------------- K3b: feat tail cols 576..583 -------------------------
__global__ __launch_bounds__(256) void k3_tail(const int* __restrict__ ccol,
        const int* __restrict__ cobj, u16* __restrict__ feat) {
    int e = blockIdx.x * 256 + threadIdx.x;
    union { u16 s[8]; uint4 q; } b;
    b.s[0] = f2bf((float)ccol[e]);
    b.s[1] = f2bf((float)cobj[e]);
    #pragma unroll
    for (int i = 2; i < 8; ++i) b.s[i] = 0;
    *(uint4*)(feat + (size_t)e * FSTRIDE + 576) = b.q;
}

// ---------------- K4: proj via MFMA, LDS-free -> emb fp32 --------------
__global__ __launch_bounds__(256) void k4_proj_mfma(const u16* __restrict__ feat,
        const u16* __restrict__ pwT, const float* __restrict__ pb,
        float* __restrict__ emb) {
    int t = threadIdx.x;
    int l = t & 63;
    int w = t >> 6;
    int m0 = blockIdx.x * 64 + w * 16;
    int col = l & 15;
    int kg = l >> 4;
    const u16* arow = feat + (size_t)(m0 + col) * FSTRIDE + kg * 8;
    const u16* brow = pwT + col * 608 + kg * 8;

    f32x4 acc[4];
    #pragma unroll
    for (int i = 0; i < 4; ++i) {
        acc[i][0] = 0.f; acc[i][1] = 0.f; acc[i][2] = 0.f; acc[i][3] = 0.f;
    }

    #pragma unroll 4
    for (int k0 = 0; k0 < 608; k0 += 32) {
        bf16x8 a;
        if (k0 + kg * 8 < 584) {
            a = *(const bf16x8*)(arow + k0);
        } else {
            #pragma unroll
            for (int j = 0; j < 8; ++j) a[j] = 0;
        }
        bf16x8 b0 = *(const bf16x8*)(brow + k0);
        bf16x8 b1 = *(const bf16x8*)(brow + 16 * 608 + k0);
        bf16x8 b2 = *(const bf16x8*)(brow + 32 * 608 + k0);
        bf16x8 b3 = *(const bf16x8*)(brow + 48 * 608 + k0);
        acc[0] = __builtin_amdgcn_mfma_f32_16x16x32_bf16(a, b0, acc[0], 0, 0, 0);
        acc[1] = __builtin_amdgcn_mfma_f32_16x16x32_bf16(a, b1, acc[1], 0, 0, 0);
        acc[2] = __builtin_amdgcn_mfma_f32_16x16x32_bf16(a, b2, acc[2], 0, 0, 0);
        acc[3] = __builtin_amdgcn_mfma_f32_16x16x32_bf16(a, b3, acc[3], 0, 0, 0);
    }

    #pragma unroll
    for (int nt = 0; nt < 4; ++nt) {
        float pbv = pb[nt * 16 + col];
        #pragma unroll
        for (int r = 0; r < 4; ++r) {
            int row = m0 + kg * 4 + r;
            emb[row * 64 + nt * 16 + col] = fmaxf(acc[nt][r] + pbv, 0.f);
        }
    }
}

// ---------------- K5: dir_pos deltas -> extras[b][4] fp32 ---------------
__global__ __launch_bounds__(256) void k5_extras(const int* __restrict__ frame,
        float* __restrict__ extras) {
    int b = blockIdx.x * 256 + threadIdx.x;
    int d[2]; float posy[2], posx[2];
    for (int f = 0; f < 2; ++f) {
        const int* fb = frame + (size_t)(f * BATCH + b) * 147;
        int idx = 49;
        for (int cell = 0; cell < 49; ++cell) {
            int v = fb[cell * 3];
            if (idx == 49 && v == 10) idx = cell;
        }
        if (idx < 49) {
            d[f] = fb[idx * 3 + 2] & 3;
            posy[f] = (float)(idx / 7) / 6.0f;
            posx[f] = (float)(idx % 7) / 6.0f;
        } else {
            d[f] = 0; posy[f] = 0.5f; posx[f] = 0.5f;
        }
    }
    int delta = (d[1] - d[0] + 4) & 3;
    const float ANG = (float)(2.0 * 3.14159 / 4.0);
    float angle = (float)delta * ANG;
    float4 o;
    o.x = sinf(angle);
    o.y = cosf(angle);
    o.z = posy[1] - posy[0];
    o.w = posx[1] - posx[0];
    *(float4*)(extras + b * 4) = o;
}

// ---------------- K6: h1 GEMM (gathered A, K=132) + bias + LN + relu ----
// R3-pass validated fp32 LDS version.
__global__ __launch_bounds__(128) void k6_h1(
        const float* __restrict__ emb, const float* __restrict__ extras,
        const float* __restrict__ w, const float* __restrict__ bias,
        const float* __restrict__ lng, const float* __restrict__ lnb,
        float* __restrict__ out) {
    __shared__ float As[64 * 133];
    __shared__ float Bs[32 * 129];
    __shared__ float mu_s[64], rs_s[64];
    int t = threadIdx.x;
    int b0 = blockIdx.x * 64;
    {
        int r = t >> 1, half = t & 1;
        int gb = b0 + r;
        for (int kk = 0; kk < 66; ++kk) {
            int k = half * 66 + kk;
            float v;
            if (k < 64)       v = emb[gb * 64 + k];
            else if (k < 128) v = emb[(BATCH + gb) * 64 + (k - 64)];
            else              v = extras[gb * 4 + (k - 128)];
            As[r * 133 + k] = v;
        }
    }
    int tm = t >> 4, tn = t & 15;
    float acc[8][8];
    #pragma unroll
    for (int i = 0; i < 8; ++i)
        #pragma unroll
        for (int j = 0; j < 8; ++j) acc[i][j] = 0.f;

    for (int k0 = 0; k0 < 132; k0 += 32) {
        int kl = 132 - k0; if (kl > 32) kl = 32;
        __syncthreads();
        for (int i = 0; i < 32; ++i) {
            int idx = i * 128 + t;
            int j = idx >> 5, kk = idx & 31;
            Bs[kk * 129 + j] = (kk < kl) ? w[j * 132 + k0 + kk] : 0.f;
        }
        __syncthreads();
        for (int kk = 0; kk < kl; ++kk) {
            float a[8], b[8];
            #pragma unroll
            for (int i = 0; i < 8; ++i) a[i] = As[(tm * 8 + i) * 133 + k0 + kk];
            #pragma unroll
            for (int j = 0; j < 8; ++j) b[j] = Bs[kk * 129 + tn + 16 * j];
            #pragma unroll
            for (int i = 0; i < 8; ++i)
                #pragma unroll
                for (int j = 0; j < 8; ++j)
                    acc[i][j] += a[i] * b[j];
        }
    }
    __syncthreads();
    float* h = As;
    #pragma unroll
    for (int i = 0; i < 8; ++i)
        #pragma unroll
        for (int j = 0; j < 8; ++j) {
            int jj = tn + 16 * j;
            h[(tm * 8 + i) * 129 + jj] = acc[i][j] + bias[jj];
        }
    __syncthreads();
    if (t < 64) {
        float s = 0.f;
        for (int k = 0; k < 128; ++k) s += h[t * 129 + k];
        float mu = s * (1.0f / 128.0f);
        float vs = 0.f;
        for (int k = 0; k < 128; ++k) { float d = h[t * 129 + k] - mu; vs += d * d; }
        mu_s[t] = mu;
        rs_s[t] = rsqrtf(vs * (1.0f / 128.0f) + 1e-5f);
    }
    __syncthreads();
    for (int i = 0; i < 64; ++i) {
        int o = i * 128 + t;
        int r = o >> 7, j = o & 127;
        float v = (h[r * 129 + j] - mu_s[r]) * rs_s[r] * lng[j] + lnb[j];
        out[(b0 + r) * 128 + j] = fmaxf(v, 0.f);
    }
}

// ---------------- K7: h2 GEMM [32768x128]@[128->128] + relu -------------
// R3-pass validated fp32 LDS version.
__global__ __launch_bounds__(128) void k7_h2(
        const float* __restrict__ in, const float* __restrict__ w,
        const float* __restrict__ bias, float* __restrict__ out) {
    __shared__ float As[64 * 129];
    __shared__ float Bs[32 * 129];
    int t = threadIdx.x;
    int b0 = blockIdx.x * 64;
    {
        int r = t >> 1, half = t & 1;
        for (int kk = 0; kk < 64; ++kk) {
            int k = half * 64 + kk;
            As[r * 129 + k] = in[(b0 + r) * 128 + k];
        }
    }
    int tm = t >> 4, tn = t & 15;
    float acc[8][8];
    #pragma unroll
    for (int i = 0; i < 8; ++i)
        #pragma unroll
        for (int j = 0; j < 8; ++j) acc[i][j] = 0.f;

    for (int k0 = 0; k0 < 128; k0 += 32) {
        __syncthreads();
        for (int i = 0; i < 32; ++i) {
            int idx = i * 128 + t;
            int j = idx >> 5, kk = idx & 31;
            Bs[kk * 129 + j] = w[j * 128 + k0 + kk];
        }
        __syncthreads();
        for (int kk = 0; kk < 32; ++kk) {
            float a[8], b[8];
            #pragma unroll
            for (int i = 0; i < 8; ++i) a[i] = As[(tm * 8 + i) * 129 + k0 + kk];
            #pragma unroll
            for (int j = 0; j < 8; ++j) b[j] = Bs[kk * 129 + tn + 16 * j];
            #pragma unroll
            for (int i = 0; i < 8; ++i)
                #pragma unroll
                for (int j = 0; j < 8; ++j)
                    acc[i][j] += a[i] * b[j];
        }
    }
    #pragma unroll
    for (int i = 0; i < 8; ++i)
        #pragma unroll
        for (int j = 0; j < 8; ++j) {
            int jj = tn + 16 * j;
            out[(b0 + tm * 8 + i) * 128 + jj] = fmaxf(acc[i][j] + bias[jj], 0.f);
        }
}

// ---------------- K8: h3 [32768x128]@[128->7], thread = row, fp32 ------
__global__ __launch_bounds__(256) void k8_h3(const float* __restrict__ in,
        const float* __restrict__ w, const float* __restrict__ bias,
        float* __restrict__ out) {
    int r = blockIdx.x * 256 + threadIdx.x;
    float acc[7];
    #pragma unroll
    for (int j = 0; j < 7; ++j) acc[j] = bias[j];
    const float* row = in + (size_t)r * 128;
    #pragma unroll 4
    for (int c = 0; c < 32; ++c) {
        float4 v = *(const float4*)(row + c * 4);
        #pragma unroll
        for (int j = 0; j < 7; ++j) {
            acc[j] += v.x * w[j * 128 + c * 4 + 0];
            acc[j] += v.y * w[j * 128 + c * 4 + 1];
            acc[j] += v.z * w[j * 128 + c * 4 + 2];
            acc[j] += v.w * w[j * 128 + c * 4 + 3];
        }
    }
    #pragma unroll
    for (int j = 0; j < 7; ++j) out[r * 7 + j] = acc[j];
}

extern "C" void kernel_launch(void* const* d_in, const int* in_sizes, int n_in,
                              void* d_out, int out_size, void* d_ws, size_t ws_size,
                              hipStream_t stream) {
    const int*   frame = (const int*)d_in[0];
    const int*   ccol  = (const int*)d_in[1];
    const int*   cobj  = (const int*)d_in[2];
    const float* w1    = (const float*)d_in[3];
    const float* b1    = (const float*)d_in[4];
    const float* w2    = (const float*)d_in[5];
    const float* b2    = (const float*)d_in[6];
    const float* w3    = (const float*)d_in[7];
    const float* b3    = (const float*)d_in[8];
    const float* pw    = (const float*)d_in[9];
    const float* pb    = (const float*)d_in[10];
    const float* h1w   = (const float*)d_in[11];
    const float* h1b   = (const float*)d_in[12];
    const float* lng   = (const float*)d_in[13];
    const float* lnb   = (const float*)d_in[14];
    const float* h2w   = (const float*)d_in[15];
    const float* h2b   = (const float*)d_in[16];
    const float* h3w   = (const float*)d_in[17];
    const float* h3b   = (const float*)d_in[18];
    float* out = (float*)d_out;

    char* ws = (char*)d_ws;
    // Region A [0,32MB): pooled1b (k1->k2); then emb fp32 (k4->k6) + extras
    // Region B [32MB,48MB): pooled2 (k2->k3); then h1out fp32 (k6->k7)
    // Region C [48MB,124.5MB): feat (k3->k4); then h2out fp32 (k7->k8)
    // Region D [126MB+): converted weights (k0 -> consumers)
    u16*   pooled1b = (u16*)(ws + 0);                    // 32 MB
    float* emb      = (float*)(ws + 0);                  // 16 MB (after k2)
    float* extras   = (float*)(ws + 16777216);           // 512 KB
    u16*   pooled2  = (u16*)(ws + 33554432);             // 16 MB
    float* h1out    = (float*)(ws + 33554432);           // 16 MB (after k3)
    u16*   feat     = (u16*)(ws + 50331648);             // 76.5 MB
    float* h2out    = (float*)(ws + 50331648);           // 16 MB (after k4)
    u16*   pwT      = (u16*)(ws + 132120576);            // 77824 B
    u16*   w2r      = (u16*)(ws + 132120576 + 131072);   // 4096 B
    u16*   w3r      = (u16*)(ws + 132120576 + 139264);   // 16384 B

    k0_prep<<<192, 256, 0, stream>>>(pw, w2, w3, pwT, w2r, w3r);
    k1_conv1<<<16384, 256, 0, stream>>>(frame, w1, b1, pooled1b);
    k2_conv2_mfma<<<1024, 256, 0, stream>>>(pooled1b, w2r, b2, pooled2);
    k3_conv3_mfma<<<1024, 256, 0, stream>>>(pooled2, w3r, b3, feat);
    k3_tail<<<256, 256, 0, stream>>>(ccol, cobj, feat);
    k4_proj_mfma<<<1024, 256, 0, stream>>>(feat, pwT, pb, emb);
    k5_extras<<<128, 256, 0, stream>>>(frame, extras);
    k6_h1<<<512, 128, 0, stream>>>(emb, extras, h1w, h1b, lng, lnb, h1out);
    k7_h2<<<512, 128, 0, stream>>>(h1out, h2w, h2b, h2out);
    k8_h3<<<128, 256, 0, stream>>>(h2out, h3w, h3b, out);
}

// Round 8
// 315.484 us; speedup vs baseline: 2.9359x; 1.0878x over previous
//
#include <hip/hip_runtime.h>
#include <hip/hip_bf16.h>

#define BATCH 32768
#define NELEM 65536   // 2 * BATCH
#define FSTRIDE 584   // feat row stride (578 cols + 6 zeroed pad cols)

typedef unsigned short u16;
typedef unsigned int u32;
typedef __attribute__((ext_vector_type(8))) short bf16x8;
typedef __attribute__((ext_vector_type(4))) float f32x4;

__device__ __forceinline__ float bf2f(u16 u) {
    union { u32 u; float f; } c; c.u = ((u32)u) << 16; return c.f;
}
__device__ __forceinline__ u16 f2bf(float f) {
    union { float f; u32 u; } c; c.f = f;
    u32 x = c.u;
    u32 r = (x + 0x7fffu + ((x >> 16) & 1u)) >> 16;  // RNE
    return (u16)r;
}

// ---------------- K0: weight prep ---------------------------------------
// pwT: [64][608]; K-order kk = p*64+oc (matches k3's coalesced feat layout),
//      kk=576/577 = carried, kk>=578 zero.
// w2r: [oc32][k=tap*16+ic]   from w2 [oc][ic][ky][kx]
// w3r: [oc64][k=tap*32+ic]   from w3 [oc][ic][ky][kx]
// h2hi/h2lo: [128][128] split-bf16 h2_w
__global__ __launch_bounds__(256) void k0_prep(const float* __restrict__ pw,
        const float* __restrict__ w2, const float* __restrict__ w3,
        const float* __restrict__ h2w,
        u16* __restrict__ pwT, u16* __restrict__ w2r, u16* __restrict__ w3r,
        u16* __restrict__ h2hi, u16* __restrict__ h2lo) {
    int idx = blockIdx.x * 256 + threadIdx.x;
    if (idx < 38912) {
        int j = idx / 608, kk = idx - j * 608;
        float v = 0.f;
        if (kk < 576) {
            int p = kk >> 6, oc = kk & 63;
            v = pw[j * 578 + oc * 9 + p];
        } else if (kk < 578) {
            v = pw[j * 578 + kk];
        }
        pwT[idx] = f2bf(v);
    } else if (idx < 40960) {
        int i = idx - 38912;
        int oc = i >> 6, rem = i & 63, tap = rem >> 4, ic = rem & 15;
        w2r[i] = f2bf(w2[oc * 64 + ic * 4 + tap]);
    } else if (idx < 49152) {
        int i = idx - 40960;
        int oc = i >> 7, rem = i & 127, tap = rem >> 5, ic = rem & 31;
        w3r[i] = f2bf(w3[oc * 128 + ic * 4 + tap]);
    } else if (idx < 65536) {
        int i = idx - 49152;
        float v = h2w[i];
        u16 hi = f2bf(v);
        h2hi[i] = hi;
        h2lo[i] = f2bf(v - bf2f(hi));
    }
}

// ---------------- K1: conv1 (pad1,k2) + relu + maxpool2 -> bf16 --------
__global__ __launch_bounds__(256) void k1_conv1(const int* __restrict__ frame,
        const float* __restrict__ w1, const float* __restrict__ b1,
        u16* __restrict__ pooled1b) {
    __shared__ float fr[4][160];
    int t = threadIdx.x;
    int le = t >> 6, l = t & 63;
    int e = blockIdx.x * 4 + le;
    #pragma unroll
    for (int i = 0; i < 3; ++i) {
        int off = i * 64 + l;
        if (off < 147) fr[le][off] = (float)frame[e * 147 + off];
    }
    __syncthreads();
    int pyc = l >> 3, pxc = l & 7;
    float p[2][2][3];
    #pragma unroll
    for (int ky = 0; ky < 2; ++ky) {
        int y = pyc - 1 + ky;
        #pragma unroll
        for (int kx = 0; kx < 2; ++kx) {
            int x = pxc - 1 + kx;
            bool ok = (y >= 0 && y < 7 && x >= 0 && x < 7);
            int base = (y * 7 + x) * 3;
            #pragma unroll
            for (int c = 0; c < 3; ++c)
                p[ky][kx][c] = ok ? fr[le][base + c] : 0.f;
        }
    }
    union { u16 s[16]; uint4 q[2]; } ob;
    #pragma unroll
    for (int oc = 0; oc < 16; ++oc) {
        float acc = b1[oc];
        #pragma unroll
        for (int ic = 0; ic < 3; ++ic)
            #pragma unroll
            for (int ky = 0; ky < 2; ++ky)
                #pragma unroll
                for (int kx = 0; kx < 2; ++kx)
                    acc += p[ky][kx][ic] * w1[oc * 12 + ic * 4 + ky * 2 + kx];
        acc = fmaxf(acc, 0.f);
        acc = fmaxf(acc, __shfl_xor(acc, 1, 64));
        acc = fmaxf(acc, __shfl_xor(acc, 8, 64));
        ob.s[oc] = f2bf(acc);
    }
    if (((pyc | pxc) & 1) == 0) {
        int pos = (pyc >> 1) * 4 + (pxc >> 1);
        uint4* outp = (uint4*)(pooled1b + e * 256 + pos * 16);
        outp[0] = ob.q[0];
        outp[1] = ob.q[1];
    }
}

// ---------------- K2: conv2+relu+maxpool fused via MFMA, LDS-free ------
#define K2_WAVES 4096
__global__ __launch_bounds__(256) void k2_conv2_mfma(const u16* __restrict__ pooled1b,
        const u16* __restrict__ w2r, const float* __restrict__ b2,
        u16* __restrict__ pooled2) {
    int t = threadIdx.x;
    int l = t & 63;
    int col = l & 15;
    int kg = l >> 4;
    int wv = (blockIdx.x * 256 + t) >> 6;

    bf16x8 bfrag[2][2];
    #pragma unroll
    for (int s = 0; s < 2; ++s)
        #pragma unroll
        for (int nt = 0; nt < 2; ++nt)
            bfrag[s][nt] = *(const bf16x8*)(w2r + (nt * 16 + col) * 64 + s * 32 + kg * 8);
    float bias[2] = { b2[col], b2[16 + col] };

    int oy = col >> 2, ox = col & 3;
    int aoff[2]; bool aok[2];
    #pragma unroll
    for (int s = 0; s < 2; ++s) {
        int tap = 2 * s + (kg >> 1);
        int ky = tap >> 1, kx = tap & 1;
        int iy = oy - 1 + ky, ix = ox - 1 + kx;
        aok[s] = (iy >= 0 && ix >= 0);
        aoff[s] = (iy * 4 + ix) * 16 + (kg & 1) * 8;
    }

    for (int e = wv; e < NELEM; e += K2_WAVES) {
        const u16* pbase = pooled1b + e * 256;
        bf16x8 a0 = {0,0,0,0,0,0,0,0}, a1 = {0,0,0,0,0,0,0,0};
        if (aok[0]) a0 = *(const bf16x8*)(pbase + aoff[0]);
        if (aok[1]) a1 = *(const bf16x8*)(pbase + aoff[1]);
        f32x4 acc0 = {0.f,0.f,0.f,0.f}, acc1 = {0.f,0.f,0.f,0.f};
        acc0 = __builtin_amdgcn_mfma_f32_16x16x32_bf16(a0, bfrag[0][0], acc0, 0, 0, 0);
        acc1 = __builtin_amdgcn_mfma_f32_16x16x32_bf16(a0, bfrag[0][1], acc1, 0, 0, 0);
        acc0 = __builtin_amdgcn_mfma_f32_16x16x32_bf16(a1, bfrag[1][0], acc0, 0, 0, 0);
        acc1 = __builtin_amdgcn_mfma_f32_16x16x32_bf16(a1, bfrag[1][1], acc1, 0, 0, 0);
        #pragma unroll
        for (int nt = 0; nt < 2; ++nt) {
            f32x4 acc = nt ? acc1 : acc0;
            float b = bias[nt];
            float m0 = fmaxf(fmaxf(acc[0] + b, 0.f), fmaxf(acc[1] + b, 0.f));
            float m1 = fmaxf(fmaxf(acc[2] + b, 0.f), fmaxf(acc[3] + b, 0.f));
            float p0 = fmaxf(m0, __shfl_xor(m0, 16, 64));
            float p1 = fmaxf(m1, __shfl_xor(m1, 16, 64));
            if ((kg & 1) == 0) {
                int q = (kg >> 1) * 2;
                u16* op = pooled2 + e * 128 + nt * 16 + col;
                op[q * 32]       = f2bf(p0);
                op[(q + 1) * 32] = f2bf(p1);
            }
        }
    }
}

// ---------------- K3: conv3+relu via MFMA, LDS-free --------------------
// feat layout: feat[elem][p*64 + oc]  (coalesced epilogue: 16-lane group
// writes 64 contiguous u16 per (r); pwT uses the same K-order).
#define K3_WAVES 4096
__global__ __launch_bounds__(256) void k3_conv3_mfma(const u16* __restrict__ pooled2,
        const u16* __restrict__ w3r, const float* __restrict__ b3,
        u16* __restrict__ feat) {
    int t = threadIdx.x;
    int l = t & 63;
    int col = l & 15;
    int kg = l >> 4;
    int wv = (blockIdx.x * 256 + t) >> 6;
    const int NTILE = (NELEM * 9) / 16;  // 36864

    bf16x8 bfrag[4][4];
    #pragma unroll
    for (int s = 0; s < 4; ++s)
        #pragma unroll
        for (int nt = 0; nt < 4; ++nt)
            bfrag[s][nt] = *(const bf16x8*)(w3r + (nt * 16 + col) * 128 + s * 32 + kg * 8);
    float bias[4];
    #pragma unroll
    for (int nt = 0; nt < 4; ++nt) bias[nt] = b3[nt * 16 + col];

    for (int mt = wv; mt < NTILE; mt += K3_WAVES) {
        int m0 = mt * 16;
        int m = m0 + col;
        u32 elem = (u32)(((unsigned long long)(u32)m * 954437177ull) >> 33); // m/9
        int p = m - (int)elem * 9;
        int oy = (p * 86) >> 8;
        int ox = p - 3 * oy;
        const u16* pbase = pooled2 + (size_t)elem * 128 + kg * 8;
        f32x4 acc[4];
        #pragma unroll
        for (int nt = 0; nt < 4; ++nt) {
            acc[nt][0] = 0.f; acc[nt][1] = 0.f; acc[nt][2] = 0.f; acc[nt][3] = 0.f;
        }
        #pragma unroll
        for (int s = 0; s < 4; ++s) {
            int ky = s >> 1, kx = s & 1;
            int iy = oy - 1 + ky, ix = ox - 1 + kx;
            bf16x8 a = {0,0,0,0,0,0,0,0};
            if (iy >= 0 && iy <= 1 && ix >= 0 && ix <= 1)
                a = *(const bf16x8*)(pbase + (iy * 2 + ix) * 32);
            #pragma unroll
            for (int nt = 0; nt < 4; ++nt)
                acc[nt] = __builtin_amdgcn_mfma_f32_16x16x32_bf16(a, bfrag[s][nt], acc[nt], 0, 0, 0);
        }
        #pragma unroll
        for (int r = 0; r < 4; ++r) {
            int mr = m0 + kg * 4 + r;
            u32 er = (u32)(((unsigned long long)(u32)mr * 954437177ull) >> 33);
            int pr = mr - (int)er * 9;
            u16* fb = feat + (size_t)er * FSTRIDE + pr * 64;
            #pragma unroll
            for (int nt = 0; nt < 4; ++nt)
                fb[nt * 16 + col] = f2bf(fmaxf(acc[nt][r] + bias[nt], 0.f));
        }
    }
}

// ---------------- K3b: feat tail cols 576..583 -------------------------
__global__ __launch_bounds__(256) void k3_tail(const int* __restrict__ ccol,
        const int* __restrict__ cobj, u16* __restrict__ feat) {
    int e = blockIdx.x * 256 + threadIdx.x;
    union { u16 s[8]; uint4 q; } b;
    b.s[0] = f2bf((float)ccol[e]);
    b.s[1] = f2bf((float)cobj[e]);
    #pragma unroll
    for (int i = 2; i < 8; ++i) b.s[i] = 0;
    *(uint4*)(feat + (size_t)e * FSTRIDE + 576) = b.q;
}

// ---------------- K4: proj via MFMA, LDS-free -> emb fp32 --------------
__global__ __launch_bounds__(256) void k4_proj_mfma(const u16* __restrict__ feat,
        const u16* __restrict__ pwT, const float* __restrict__ pb,
        float* __restrict__ emb) {
    int t = threadIdx.x;
    int l = t & 63;
    int w = t >> 6;
    int m0 = blockIdx.x * 64 + w * 16;
    int col = l & 15;
    int kg = l >> 4;
    const u16* arow = feat + (size_t)(m0 + col) * FSTRIDE + kg * 8;
    const u16* brow = pwT + col * 608 + kg * 8;

    f32x4 acc[4];
    #pragma unroll
    for (int i = 0; i < 4; ++i) {
        acc[i][0] = 0.f; acc[i][1] = 0.f; acc[i][2] = 0.f; acc[i][3] = 0.f;
    }

    #pragma unroll 4
    for (int k0 = 0; k0 < 608; k0 += 32) {
        bf16x8 a;
        if (k0 + kg * 8 < 584) {
            a = *(const bf16x8*)(arow + k0);
        } else {
            #pragma unroll
            for (int j = 0; j < 8; ++j) a[j] = 0;
        }
        bf16x8 b0 = *(const bf16x8*)(brow + k0);
        bf16x8 b1 = *(const bf16x8*)(brow + 16 * 608 + k0);
        bf16x8 b2 = *(const bf16x8*)(brow + 32 * 608 + k0);
        bf16x8 b3 = *(const bf16x8*)(brow + 48 * 608 + k0);
        acc[0] = __builtin_amdgcn_mfma_f32_16x16x32_bf16(a, b0, acc[0], 0, 0, 0);
        acc[1] = __builtin_amdgcn_mfma_f32_16x16x32_bf16(a, b1, acc[1], 0, 0, 0);
        acc[2] = __builtin_amdgcn_mfma_f32_16x16x32_bf16(a, b2, acc[2], 0, 0, 0);
        acc[3] = __builtin_amdgcn_mfma_f32_16x16x32_bf16(a, b3, acc[3], 0, 0, 0);
    }

    #pragma unroll
    for (int nt = 0; nt < 4; ++nt) {
        float pbv = pb[nt * 16 + col];
        #pragma unroll
        for (int r = 0; r < 4; ++r) {
            int row = m0 + kg * 4 + r;
            emb[row * 64 + nt * 16 + col] = fmaxf(acc[nt][r] + pbv, 0.f);
        }
    }
}

// ---------------- K5: dir_pos deltas -> extras[b][4] fp32 ---------------
__global__ __launch_bounds__(256) void k5_extras(const int* __restrict__ frame,
        float* __restrict__ extras) {
    int b = blockIdx.x * 256 + threadIdx.x;
    int d[2]; float posy[2], posx[2];
    for (int f = 0; f < 2; ++f) {
        const int* fb = frame + (size_t)(f * BATCH + b) * 147;
        int idx = 49;
        for (int cell = 0; cell < 49; ++cell) {
            int v = fb[cell * 3];
            if (idx == 49 && v == 10) idx = cell;
        }
        if (idx < 49) {
            d[f] = fb[idx * 3 + 2] & 3;
            posy[f] = (float)(idx / 7) / 6.0f;
            posx[f] = (float)(idx % 7) / 6.0f;
        } else {
            d[f] = 0; posy[f] = 0.5f; posx[f] = 0.5f;
        }
    }
    int delta = (d[1] - d[0] + 4) & 3;
    const float ANG = (float)(2.0 * 3.14159 / 4.0);
    float angle = (float)delta * ANG;
    float4 o;
    o.x = sinf(angle);
    o.y = cosf(angle);
    o.z = posy[1] - posy[0];
    o.w = posx[1] - posx[0];
    *(float4*)(extras + b * 4) = o;
}

// ---------------- K6: h1 GEMM (gathered A, K=132) + bias + LN + relu ----
// R3-pass validated fp32 LDS version.
__global__ __launch_bounds__(128) void k6_h1(
        const float* __restrict__ emb, const float* __restrict__ extras,
        const float* __restrict__ w, const float* __restrict__ bias,
        const float* __restrict__ lng, const float* __restrict__ lnb,
        float* __restrict__ out) {
    __shared__ float As[64 * 133];
    __shared__ float Bs[32 * 129];
    __shared__ float mu_s[64], rs_s[64];
    int t = threadIdx.x;
    int b0 = blockIdx.x * 64;
    {
        int r = t >> 1, half = t & 1;
        int gb = b0 + r;
        for (int kk = 0; kk < 66; ++kk) {
            int k = half * 66 + kk;
            float v;
            if (k < 64)       v = emb[gb * 64 + k];
            else if (k < 128) v = emb[(BATCH + gb) * 64 + (k - 64)];
            else              v = extras[gb * 4 + (k - 128)];
            As[r * 133 + k] = v;
        }
    }
    int tm = t >> 4, tn = t & 15;
    float acc[8][8];
    #pragma unroll
    for (int i = 0; i < 8; ++i)
        #pragma unroll
        for (int j = 0; j < 8; ++j) acc[i][j] = 0.f;

    for (int k0 = 0; k0 < 132; k0 += 32) {
        int kl = 132 - k0; if (kl > 32) kl = 32;
        __syncthreads();
        for (int i = 0; i < 32; ++i) {
            int idx = i * 128 + t;
            int j = idx >> 5, kk = idx & 31;
            Bs[kk * 129 + j] = (kk < kl) ? w[j * 132 + k0 + kk] : 0.f;
        }
        __syncthreads();
        for (int kk = 0; kk < kl; ++kk) {
            float a[8], b[8];
            #pragma unroll
            for (int i = 0; i < 8; ++i) a[i] = As[(tm * 8 + i) * 133 + k0 + kk];
            #pragma unroll
            for (int j = 0; j < 8; ++j) b[j] = Bs[kk * 129 + tn + 16 * j];
            #pragma unroll
            for (int i = 0; i < 8; ++i)
                #pragma unroll
                for (int j = 0; j < 8; ++j)
                    acc[i][j] += a[i] * b[j];
        }
    }
    __syncthreads();
    float* h = As;
    #pragma unroll
    for (int i = 0; i < 8; ++i)
        #pragma unroll
        for (int j = 0; j < 8; ++j) {
            int jj = tn + 16 * j;
            h[(tm * 8 + i) * 129 + jj] = acc[i][j] + bias[jj];
        }
    __syncthreads();
    if (t < 64) {
        float s = 0.f;
        for (int k = 0; k < 128; ++k) s += h[t * 129 + k];
        float mu = s * (1.0f / 128.0f);
        float vs = 0.f;
        for (int k = 0; k < 128; ++k) { float d = h[t * 129 + k] - mu; vs += d * d; }
        mu_s[t] = mu;
        rs_s[t] = rsqrtf(vs * (1.0f / 128.0f) + 1e-5f);
    }
    __syncthreads();
    for (int i = 0; i < 64; ++i) {
        int o = i * 128 + t;
        int r = o >> 7, j = o & 127;
        float v = (h[r * 129 + j] - mu_s[r]) * rs_s[r] * lng[j] + lnb[j];
        out[(b0 + r) * 128 + j] = fmaxf(v, 0.f);
    }
}

__device__ __forceinline__ void split8(const float* __restrict__ x,
                                       bf16x8& hi, bf16x8& lo) {
    #pragma unroll
    for (int j = 0; j < 8; ++j) {
        u16 h = f2bf(x[j]);
        hi[j] = (short)h;
        lo[j] = (short)f2bf(x[j] - bf2f(h));
    }
}

// ---------------- K7: h2 via split-bf16 MFMA (fp32 in, fp32 out) -------
// Bisection step 2: ONLY k7 uses the MFMA-MLP pattern this round.
__global__ __launch_bounds__(256) void k7_h2_mfma(const float* __restrict__ in,
        const u16* __restrict__ whi, const u16* __restrict__ wlo,
        const float* __restrict__ bias, float* __restrict__ out) {
    int t = threadIdx.x;
    int l = t & 63;
    int col = l & 15;
    int kg = l >> 4;
    int m0 = blockIdx.x * 64 + (t >> 6) * 16;
    const float* arow = in + (size_t)(m0 + col) * 128 + kg * 8;
    const u16* bh = whi + col * 128 + kg * 8;
    const u16* bl = wlo + col * 128 + kg * 8;

    f32x4 acc[8];
    #pragma unroll
    for (int nt = 0; nt < 8; ++nt) {
        acc[nt][0] = 0.f; acc[nt][1] = 0.f; acc[nt][2] = 0.f; acc[nt][3] = 0.f;
    }
    #pragma unroll
    for (int s = 0; s < 4; ++s) {
        float x[8];
        #pragma unroll
        for (int j = 0; j < 8; ++j) x[j] = arow[s * 32 + j];
        bf16x8 ahi, alo;
        split8(x, ahi, alo);
        #pragma unroll
        for (int nt = 0; nt < 8; ++nt) {
            bf16x8 bhiF = *(const bf16x8*)(bh + nt * 2048 + s * 32);
            bf16x8 bloF = *(const bf16x8*)(bl + nt * 2048 + s * 32);
            acc[nt] = __builtin_amdgcn_mfma_f32_16x16x32_bf16(ahi, bhiF, acc[nt], 0, 0, 0);
            acc[nt] = __builtin_amdgcn_mfma_f32_16x16x32_bf16(alo, bhiF, acc[nt], 0, 0, 0);
            acc[nt] = __builtin_amdgcn_mfma_f32_16x16x32_bf16(ahi, bloF, acc[nt], 0, 0, 0);
        }
    }
    #pragma unroll
    for (int nt = 0; nt < 8; ++nt) {
        float bv = bias[nt * 16 + col];
        #pragma unroll
        for (int r = 0; r < 4; ++r) {
            int m = m0 + kg * 4 + r;
            out[m * 128 + nt * 16 + col] = fmaxf(acc[nt][r] + bv, 0.f);
        }
    }
}

// ---------------- K8: h3 [32768x128]@[128->7], thread = row, fp32 ------
__global__ __launch_bounds__(256) void k8_h3(const float* __restrict__ in,
        const float* __restrict__ w, const float* __restrict__ bias,
        float* __restrict__ out) {
    int r = blockIdx.x * 256 + threadIdx.x;
    float acc[7];
    #pragma unroll
    for (int j = 0; j < 7; ++j) acc[j] = bias[j];
    const float* row = in + (size_t)r * 128;
    #pragma unroll 4
    for (int c = 0; c < 32; ++c) {
        float4 v = *(const float4*)(row + c * 4);
        #pragma unroll
        for (int j = 0; j < 7; ++j) {
            acc[j] += v.x * w[j * 128 + c * 4 + 0];
            acc[j] += v.y * w[j * 128 + c * 4 + 1];
            acc[j] += v.z * w[j * 128 + c * 4 + 2];
            acc[j] += v.w * w[j * 128 + c * 4 + 3];
        }
    }
    #pragma unroll
    for (int j = 0; j < 7; ++j) out[r * 7 + j] = acc[j];
}

extern "C" void kernel_launch(void* const* d_in, const int* in_sizes, int n_in,
                              void* d_out, int out_size, void* d_ws, size_t ws_size,
                              hipStream_t stream) {
    const int*   frame = (const int*)d_in[0];
    const int*   ccol  = (const int*)d_in[1];
    const int*   cobj  = (const int*)d_in[2];
    const float* w1    = (const float*)d_in[3];
    const float* b1    = (const float*)d_in[4];
    const float* w2    = (const float*)d_in[5];
    const float* b2    = (const float*)d_in[6];
    const float* w3    = (const float*)d_in[7];
    const float* b3    = (const float*)d_in[8];
    const float* pw    = (const float*)d_in[9];
    const float* pb    = (const float*)d_in[10];
    const float* h1w   = (const float*)d_in[11];
    const float* h1b   = (const float*)d_in[12];
    const float* lng   = (const float*)d_in[13];
    const float* lnb   = (const float*)d_in[14];
    const float* h2w   = (const float*)d_in[15];
    const float* h2b   = (const float*)d_in[16];
    const float* h3w   = (const float*)d_in[17];
    const float* h3b   = (const float*)d_in[18];
    float* out = (float*)d_out;

    char* ws = (char*)d_ws;
    // Region A [0,32MB): pooled1b (k1->k2); then emb fp32 (k4->k6) + extras
    // Region B [32MB,48MB): pooled2 (k2->k3); then h1out fp32 (k6->k7)
    // Region C [48MB,124.5MB): feat (k3->k4); then h2out fp32 (k7->k8)
    // Region D [126MB+): converted weights (k0 -> consumers)
    u16*   pooled1b = (u16*)(ws + 0);                    // 32 MB
    float* emb      = (float*)(ws + 0);                  // 16 MB (after k2)
    float* extras   = (float*)(ws + 16777216);           // 512 KB
    u16*   pooled2  = (u16*)(ws + 33554432);             // 16 MB
    float* h1out    = (float*)(ws + 33554432);           // 16 MB (after k3)
    u16*   feat     = (u16*)(ws + 50331648);             // 76.5 MB
    float* h2out    = (float*)(ws + 50331648);           // 16 MB (after k4)
    u16*   pwT      = (u16*)(ws + 132120576);            // 77824 B
    u16*   w2r      = (u16*)(ws + 132120576 + 131072);   // 4096 B
    u16*   w3r      = (u16*)(ws + 132120576 + 139264);   // 16384 B
    u16*   h2hi     = (u16*)(ws + 132120576 + 163840);   // 32768 B
    u16*   h2lo     = (u16*)(ws + 132120576 + 196608);   // 32768 B

    k0_prep<<<256, 256, 0, stream>>>(pw, w2, w3, h2w, pwT, w2r, w3r, h2hi, h2lo);
    k1_conv1<<<16384, 256, 0, stream>>>(frame, w1, b1, pooled1b);
    k2_conv2_mfma<<<1024, 256, 0, stream>>>(pooled1b, w2r, b2, pooled2);
    k3_conv3_mfma<<<1024, 256, 0, stream>>>(pooled2, w3r, b3, feat);
    k3_tail<<<256, 256, 0, stream>>>(ccol, cobj, feat);
    k4_proj_mfma<<<1024, 256, 0, stream>>>(feat, pwT, pb, emb);
    k5_extras<<<128, 256, 0, stream>>>(frame, extras);
    k6_h1<<<512, 128, 0, stream>>>(emb, extras, h1w, h1b, lng, lnb, h1out);
    k7_h2_mfma<<<512, 256, 0, stream>>>(h1out, h2hi, h2lo, h2b, h2out);
    k8_h3<<<128, 256, 0, stream>>>(h2out, h3w, h3b, out);
}